// Round 1
// baseline (8162.243 us; speedup 1.0000x reference)
//
#include <hip/hip_runtime.h>
#include <math.h>

#define GF_BIAS   1
#define GF_RELU   2
#define GF_RESID  4
#define GF_POSENC 8

namespace {
constexpr int BB = 4, SS = 1024, DIN_ = 768, DD = 224, HHh = 8, DKK = 28, FFF = 600, VV = 8000, LLl = 8;
constexpr int MT = BB * SS;          // 4096 tokens
constexpr int QKV_N = 3 * DD;        // 672

constexpr size_t OFF_H   = 0;
constexpr size_t OFF_H2  = OFF_H  + (size_t)MT * DD;                 // 917504
constexpr size_t OFF_O   = OFF_H2 + (size_t)MT * DD;
constexpr size_t OFF_WT  = OFF_O  + (size_t)MT * DD;                 // L*D*672 = 1204224
constexpr size_t OFF_BC  = OFF_WT + (size_t)LLl * DD * QKV_N;        // L*672
constexpr size_t OFF_BIG = OFF_BC + (size_t)LLl * QKV_N;             // max(qkv, f1+f2) = 4915200
constexpr size_t OFF_ST  = OFF_BIG + (size_t)2 * MT * FFF;           // 8 floats of LN stats
}

// ---------------------------------------------------------------------------
// Generic 128x128 fp32 GEMM: C[M,N] = A[M,K] @ B[K,N] (+bias,+resid,+posenc,relu)
// M is always 4096 (multiple of 128). N,K arbitrary (guarded).
// ---------------------------------------------------------------------------
__global__ __launch_bounds__(256) void gemm128(
    const float* __restrict__ A, const float* __restrict__ Bw,
    const float* __restrict__ bias, const float* __restrict__ Rz,
    float* __restrict__ C, int N, int K, int flags)
{
  const int t  = threadIdx.x;
  const int tx = t & 15, ty = t >> 4;
  const int m0 = blockIdx.y * 128, n0 = blockIdx.x * 128;
  __shared__ float As[16][132];
  __shared__ float Bs[16][132];
  float acc[8][8];
#pragma unroll
  for (int i = 0; i < 8; ++i)
#pragma unroll
    for (int j = 0; j < 8; ++j) acc[i][j] = 0.f;

  for (int k0 = 0; k0 < K; k0 += 16) {
    const bool fullk = (k0 + 16 <= K);
    // stage A tile 128x16 (transposed into As[k][m])
#pragma unroll
    for (int i = 0; i < 2; ++i) {
      int idx = t + i * 256;
      int r  = idx >> 2;
      int kg = (idx & 3) << 2;
      const float* ap = A + (size_t)(m0 + r) * K + (k0 + kg);
      float4 v;
      if (fullk) {
        v = *reinterpret_cast<const float4*>(ap);
      } else {
        v.x = (k0 + kg + 0 < K) ? ap[0] : 0.f;
        v.y = (k0 + kg + 1 < K) ? ap[1] : 0.f;
        v.z = (k0 + kg + 2 < K) ? ap[2] : 0.f;
        v.w = (k0 + kg + 3 < K) ? ap[3] : 0.f;
      }
      As[kg + 0][r] = v.x; As[kg + 1][r] = v.y;
      As[kg + 2][r] = v.z; As[kg + 3][r] = v.w;
    }
    // stage B tile 16x128
#pragma unroll
    for (int i = 0; i < 2; ++i) {
      int idx = t + i * 256;
      int kk = idx >> 5;
      int c4 = (idx & 31) << 2;
      int gn = n0 + c4;
      float4 v = make_float4(0.f, 0.f, 0.f, 0.f);
      if (k0 + kk < K) {
        const float* bp2 = Bw + (size_t)(k0 + kk) * N + gn;
        if (gn + 3 < N) v = *reinterpret_cast<const float4*>(bp2);
        else {
          if (gn + 0 < N) v.x = bp2[0];
          if (gn + 1 < N) v.y = bp2[1];
          if (gn + 2 < N) v.z = bp2[2];
          if (gn + 3 < N) v.w = bp2[3];
        }
      }
      *reinterpret_cast<float4*>(&Bs[kk][c4]) = v;
    }
    __syncthreads();
#pragma unroll
    for (int kk = 0; kk < 16; ++kk) {
      float a[8], bfr[8];
      *reinterpret_cast<float4*>(&a[0])   = *reinterpret_cast<const float4*>(&As[kk][ty * 4]);
      *reinterpret_cast<float4*>(&a[4])   = *reinterpret_cast<const float4*>(&As[kk][64 + ty * 4]);
      *reinterpret_cast<float4*>(&bfr[0]) = *reinterpret_cast<const float4*>(&Bs[kk][tx * 4]);
      *reinterpret_cast<float4*>(&bfr[4]) = *reinterpret_cast<const float4*>(&Bs[kk][64 + tx * 4]);
#pragma unroll
      for (int i = 0; i < 8; ++i)
#pragma unroll
        for (int j = 0; j < 8; ++j)
          acc[i][j] = fmaf(a[i], bfr[j], acc[i][j]);
    }
    __syncthreads();
  }

#pragma unroll
  for (int i = 0; i < 8; ++i) {
    const int gm = m0 + ((i < 4) ? (ty * 4 + i) : (64 + ty * 4 + i - 4));
    const int srow = gm & (SS - 1);
    const size_t rowoff = (size_t)gm * N;
#pragma unroll
    for (int jh = 0; jh < 2; ++jh) {
      const int gn0 = n0 + jh * 64 + tx * 4;
      float outv[4];
#pragma unroll
      for (int c = 0; c < 4; ++c) {
        const int gn = gn0 + c;
        float v = acc[i][jh * 4 + c];
        if (gn < N) {
          if (flags & GF_BIAS)  v += bias[gn];
          if (flags & GF_RESID) v += Rz[rowoff + gn];
          if (flags & GF_POSENC) {
            // pos_enc(s,d): ang = s / 10000^(2d/D); even d -> sin, odd -> cos
            float freq = expf(-(2.0f * gn / (float)DD) * 9.210340371976184f);
            float ang = (float)srow * freq;
            v += (gn & 1) ? cosf(ang) : sinf(ang);
          }
          if (flags & GF_RELU) v = fmaxf(v, 0.f);
        }
        outv[c] = v;
      }
      if (gn0 + 3 < N) {
        float4 sv; sv.x = outv[0]; sv.y = outv[1]; sv.z = outv[2]; sv.w = outv[3];
        *reinterpret_cast<float4*>(&C[rowoff + gn0]) = sv;
      } else {
#pragma unroll
        for (int c = 0; c < 4; ++c)
          if (gn0 + c < N) C[rowoff + gn0 + c] = outv[c];
      }
    }
  }
}

// ---------------------------------------------------------------------------
// Repack Wq/Wk/Wv (L,H,D,DK) -> Wt (L,D,3*D) with cols [q | k | v], col=h*DK+kk
// and concat biases (L,H,DK) -> (L, 3*D).
// ---------------------------------------------------------------------------
__global__ void prep_qkv(const float* __restrict__ Wq, const float* __restrict__ Wk,
                         const float* __restrict__ Wv, const float* __restrict__ bq,
                         const float* __restrict__ bk, const float* __restrict__ bv,
                         float* __restrict__ Wt, float* __restrict__ bcat)
{
  const int idx = blockIdx.x * 256 + threadIdx.x;
  const int total = LLl * HHh * DD * DKK;
  if (idx < total) {
    int kk = idx % DKK;
    int d  = (idx / DKK) % DD;
    int h  = (idx / (DKK * DD)) % HHh;
    int l  = idx / (DKK * DD * HHh);
    size_t dst = ((size_t)l * DD + d) * QKV_N;
    int col = h * DKK + kk;
    Wt[dst + col]            = Wq[idx];
    Wt[dst + DD + col]       = Wk[idx];
    Wt[dst + 2 * DD + col]   = Wv[idx];
  }
  if (idx < LLl * HHh * DKK) {
    int kk = idx % DKK;
    int h  = (idx / DKK) % HHh;
    int l  = idx / (DKK * HHh);
    int col = h * DKK + kk;
    bcat[(size_t)l * QKV_N + col]          = bq[idx];
    bcat[(size_t)l * QKV_N + DD + col]     = bk[idx];
    bcat[(size_t)l * QKV_N + 2 * DD + col] = bv[idx];
  }
}

// ---------------------------------------------------------------------------
// Flash attention, fp32. Grid: (B*H, S/256). One q-row per thread.
// qkv layout: [token][672] = [q(0..223) | k(224..447) | v(448..671)], col=h*28+kk
// o layout:   [token][224], col = h*28+kk  (matches 'bqhk' reshape)
// ---------------------------------------------------------------------------
__global__ __launch_bounds__(256) void attn_flash(const float* __restrict__ qkv,
                                                  float* __restrict__ o)
{
  const int bh = blockIdx.x;
  const int qt = blockIdx.y;
  const int b = bh >> 3, h = bh & 7;
  const int tid = threadIdx.x;
  const int qrow = qt * 256 + tid;
  const float scale = 0.1889822365046136f;  // 1/sqrt(28)

  float qv[DKK], acc[DKK];
  {
    const float* qp = qkv + (size_t)(b * SS + qrow) * QKV_N + h * DKK;
#pragma unroll
    for (int j = 0; j < DKK; ++j) { qv[j] = qp[j] * scale; acc[j] = 0.f; }
  }
  float mrun = -INFINITY, lrun = 0.f;

  __shared__ float Ks[32][DKK];
  __shared__ float Vs[32][DKK];
  const int ntiles = (qt + 1) * 8;  // kv tiles of 32 up to block's max q
  for (int tile = 0; tile < ntiles; ++tile) {
    const int t0 = tile * 32;
    __syncthreads();
    for (int idx = tid; idx < 32 * DKK; idx += 256) {
      int r = idx / DKK, c = idx - r * DKK;
      const float* kp = qkv + (size_t)(b * SS + t0 + r) * QKV_N + h * DKK + c;
      Ks[r][c] = kp[DD];
      Vs[r][c] = kp[2 * DD];
    }
    __syncthreads();

    float sc[32];
    float tmax = -INFINITY;
#pragma unroll
    for (int s2 = 0; s2 < 32; ++s2) {
      float d0 = 0.f;
#pragma unroll
      for (int j = 0; j < DKK; ++j) d0 = fmaf(qv[j], Ks[s2][j], d0);
      sc[s2] = ((t0 + s2) <= qrow) ? d0 : -INFINITY;
      tmax = fmaxf(tmax, sc[s2]);
    }
    if (tmax > -INFINITY) {
      float mnew = fmaxf(mrun, tmax);
      float r2 = __expf(mrun - mnew);  // mrun=-inf first tile -> 0
      lrun *= r2;
#pragma unroll
      for (int j = 0; j < DKK; ++j) acc[j] *= r2;
#pragma unroll
      for (int s2 = 0; s2 < 32; ++s2) {
        float p = __expf(sc[s2] - mnew);  // masked: exp(-inf)=0
        lrun += p;
#pragma unroll
        for (int j = 0; j < DKK; ++j) acc[j] = fmaf(p, Vs[s2][j], acc[j]);
      }
      mrun = mnew;
    }
  }
  const float inv = 1.0f / lrun;
  float* op = o + (size_t)(b * SS + qrow) * DD + h * DKK;
#pragma unroll
  for (int j = 0; j < DKK; ++j) op[j] = acc[j] * inv;
}

// ---------------------------------------------------------------------------
// LayerNorm over (S,D) per batch. Stats: one block per batch.
// ---------------------------------------------------------------------------
__global__ __launch_bounds__(256) void ln_stats(const float* __restrict__ x,
                                                float* __restrict__ stats)
{
  const int b = blockIdx.x;
  const int tid = threadIdx.x;
  const float* xb = x + (size_t)b * SS * DD;
  constexpr int NEL = SS * DD;  // 229376
  float sum = 0.f, sq = 0.f;
  for (int i = tid * 4; i < NEL; i += 1024) {
    float4 v = *reinterpret_cast<const float4*>(&xb[i]);
    sum += v.x + v.y + v.z + v.w;
    sq  += v.x * v.x + v.y * v.y + v.z * v.z + v.w * v.w;
  }
  __shared__ float sA[256], sB[256];
  sA[tid] = sum; sB[tid] = sq;
  __syncthreads();
  for (int s2 = 128; s2 > 0; s2 >>= 1) {
    if (tid < s2) { sA[tid] += sA[tid + s2]; sB[tid] += sB[tid + s2]; }
    __syncthreads();
  }
  if (tid == 0) {
    float mu = sA[0] / NEL;
    float var = sB[0] / NEL - mu * mu;
    stats[2 * b] = mu;
    stats[2 * b + 1] = 1.0f / sqrtf(var + 1e-5f);
  }
}

__global__ __launch_bounds__(256) void ln_apply(
    const float* __restrict__ x, const float* __restrict__ w, const float* __restrict__ bb,
    const float* __restrict__ stats, float* __restrict__ y)
{
  const size_t i4 = ((size_t)blockIdx.x * 256 + threadIdx.x) * 4;
  const int b = (int)(i4 / ((size_t)SS * DD));
  const size_t sd = i4 - (size_t)b * SS * DD;
  const float mu = stats[2 * b], rstd = stats[2 * b + 1];
  float4 xv  = *reinterpret_cast<const float4*>(&x[i4]);
  float4 wv  = *reinterpret_cast<const float4*>(&w[sd]);
  float4 bv2 = *reinterpret_cast<const float4*>(&bb[sd]);
  float4 r;
  r.x = (xv.x - mu) * rstd * wv.x + bv2.x;
  r.y = (xv.y - mu) * rstd * wv.y + bv2.y;
  r.z = (xv.z - mu) * rstd * wv.z + bv2.z;
  r.w = (xv.w - mu) * rstd * wv.w + bv2.w;
  *reinterpret_cast<float4*>(&y[i4]) = r;
}

// ---------------------------------------------------------------------------
// Row softmax over V=8000, in place on d_out. One block per row, row in LDS.
// ---------------------------------------------------------------------------
__global__ __launch_bounds__(256) void softmax_rows(float* __restrict__ logits)
{
  const int row = blockIdx.x;
  float* p = logits + (size_t)row * VV;
  __shared__ float buf[VV];
  __shared__ float red[4];
  const int tid = threadIdx.x;

  float mx = -INFINITY;
  for (int i = tid; i < VV; i += 256) { float v = p[i]; buf[i] = v; mx = fmaxf(mx, v); }
#pragma unroll
  for (int o2 = 32; o2 > 0; o2 >>= 1) mx = fmaxf(mx, __shfl_down(mx, o2));
  if ((tid & 63) == 0) red[tid >> 6] = mx;
  __syncthreads();
  mx = fmaxf(fmaxf(red[0], red[1]), fmaxf(red[2], red[3]));
  __syncthreads();

  float s = 0.f;
  for (int i = tid; i < VV; i += 256) { float e = __expf(buf[i] - mx); buf[i] = e; s += e; }
#pragma unroll
  for (int o2 = 32; o2 > 0; o2 >>= 1) s += __shfl_down(s, o2);
  if ((tid & 63) == 0) red[tid >> 6] = s;
  __syncthreads();
  s = red[0] + red[1] + red[2] + red[3];
  const float inv = 1.0f / s;
  for (int i = tid; i < VV; i += 256) p[i] = buf[i] * inv;
}

// ---------------------------------------------------------------------------
extern "C" void kernel_launch(void* const* d_in, const int* in_sizes, int n_in,
                              void* d_out, int out_size, void* d_ws, size_t ws_size,
                              hipStream_t stream) {
  const float* x   = (const float*)d_in[0];
  const float* Wp  = (const float*)d_in[1];
  const float* bp  = (const float*)d_in[2];
  const float* Wq  = (const float*)d_in[3];
  const float* bq  = (const float*)d_in[4];
  const float* Wk  = (const float*)d_in[5];
  const float* bk  = (const float*)d_in[6];
  const float* Wv  = (const float*)d_in[7];
  const float* bv  = (const float*)d_in[8];
  const float* Wo  = (const float*)d_in[9];
  const float* bo  = (const float*)d_in[10];
  const float* W1  = (const float*)d_in[11];
  const float* b1  = (const float*)d_in[12];
  const float* W2  = (const float*)d_in[13];
  const float* b2  = (const float*)d_in[14];
  const float* W3  = (const float*)d_in[15];
  const float* b3  = (const float*)d_in[16];
  const float* lnw = (const float*)d_in[17];
  const float* lnb = (const float*)d_in[18];
  const float* Wf  = (const float*)d_in[19];
  const float* bf  = (const float*)d_in[20];

  float* ws   = (float*)d_ws;
  float* h    = ws + OFF_H;
  float* h2   = ws + OFF_H2;
  float* obuf = ws + OFF_O;
  float* wt   = ws + OFF_WT;
  float* bc   = ws + OFF_BC;
  float* qkv  = ws + OFF_BIG;
  float* f1   = ws + OFF_BIG;
  float* f2   = ws + OFF_BIG + (size_t)MT * FFF;
  float* st   = ws + OFF_ST;

  // repack qkv weights/biases
  prep_qkv<<<(LLl * HHh * DD * DKK + 255) / 256, 256, 0, stream>>>(Wq, Wk, Wv, bq, bk, bv, wt, bc);

  // h = x @ Wp + bp + posenc
  gemm128<<<dim3(2, 32), 256, 0, stream>>>(x, Wp, bp, nullptr, h, DD, DIN_, GF_BIAS | GF_POSENC);

  for (int l = 0; l < LLl; ++l) {
    const float* wtl = wt + (size_t)l * DD * QKV_N;
    const float* bcl = bc + (size_t)l * QKV_N;
    // qkv = h @ [Wq|Wk|Wv] + [bq|bk|bv]
    gemm128<<<dim3(6, 32), 256, 0, stream>>>(h, wtl, bcl, nullptr, qkv, QKV_N, DD, GF_BIAS);
    // flash attention -> obuf
    attn_flash<<<dim3(BB * HHh, SS / 256), 256, 0, stream>>>(qkv, obuf);
    // h2 = obuf @ Wo + bo + h   (residual)
    gemm128<<<dim3(2, 32), 256, 0, stream>>>(obuf, Wo + (size_t)l * DD * DD,
                                             bo + (size_t)l * DD, h, h2, DD, DD,
                                             GF_BIAS | GF_RESID);
    // h = LN(h2)
    ln_stats<<<BB, 256, 0, stream>>>(h2, st);
    ln_apply<<<(MT * DD / 4 + 255) / 256, 256, 0, stream>>>(
        h2, lnw + (size_t)l * SS * DD, lnb + (size_t)l * SS * DD, st, h);
    // f1 = relu(h @ W1 + b1)
    gemm128<<<dim3(5, 32), 256, 0, stream>>>(h, W1 + (size_t)l * DD * FFF,
                                             b1 + (size_t)l * FFF, nullptr, f1, FFF, DD,
                                             GF_BIAS | GF_RELU);
    // f2 = relu(f1 @ W2 + b2)
    gemm128<<<dim3(5, 32), 256, 0, stream>>>(f1, W2 + (size_t)l * FFF * FFF,
                                             b2 + (size_t)l * FFF, nullptr, f2, FFF, FFF,
                                             GF_BIAS | GF_RELU);
    // h2 = f2 @ W3 + b3 + h   (residual)
    gemm128<<<dim3(2, 32), 256, 0, stream>>>(f2, W3 + (size_t)l * FFF * DD,
                                             b3 + (size_t)l * DD, h, h2, DD, FFF,
                                             GF_BIAS | GF_RESID);
    // h2 = LN(h2); h = LN(h2)
    ln_stats<<<BB, 256, 0, stream>>>(h2, st);
    ln_apply<<<(MT * DD / 4 + 255) / 256, 256, 0, stream>>>(
        h2, lnw + (size_t)l * SS * DD, lnb + (size_t)l * SS * DD, st, h2);
    ln_stats<<<BB, 256, 0, stream>>>(h2, st);
    ln_apply<<<(MT * DD / 4 + 255) / 256, 256, 0, stream>>>(
        h2, lnw + (size_t)l * SS * DD, lnb + (size_t)l * SS * DD, st, h);
  }

  // logits = h @ Wf + bf -> d_out, then row softmax
  gemm128<<<dim3(63, 32), 256, 0, stream>>>(h, Wf, bf, nullptr, (float*)d_out, VV, DD, GF_BIAS);
  softmax_rows<<<MT, 256, 0, stream>>>((float*)d_out);
}

// Round 2
// 5042.580 us; speedup vs baseline: 1.6187x; 1.6187x over previous
//
#include <hip/hip_runtime.h>
#include <math.h>

#define GF_BIAS   1
#define GF_RELU   2
#define GF_RESID  4
#define GF_POSENC 8

namespace {
constexpr int BB = 4, SS = 1024, DIN_ = 768, DD = 224, HHh = 8, DKK = 28, FFF = 600, VV = 8000, LLl = 8;
constexpr int MT = BB * SS;          // 4096 tokens
constexpr int QKV_N = 3 * DD;        // 672

constexpr size_t OFF_H   = 0;
constexpr size_t OFF_H2  = OFF_H  + (size_t)MT * DD;
constexpr size_t OFF_O   = OFF_H2 + (size_t)MT * DD;
constexpr size_t OFF_WT  = OFF_O  + (size_t)MT * DD;
constexpr size_t OFF_BC  = OFF_WT + (size_t)LLl * DD * QKV_N;
constexpr size_t OFF_BIG = OFF_BC + (size_t)LLl * QKV_N;
constexpr size_t OFF_ST  = OFF_BIG + (size_t)2 * MT * FFF;   // B*64*2 partial sums
}

// ---------------------------------------------------------------------------
// Generic 128x128 fp32 GEMM: C[M,N] = A[M,K] @ B[K,N] (+bias,+resid,+posenc,relu)
// ---------------------------------------------------------------------------
__global__ __launch_bounds__(256) void gemm128(
    const float* __restrict__ A, const float* __restrict__ Bw,
    const float* __restrict__ bias, const float* __restrict__ Rz,
    float* __restrict__ C, int N, int K, int flags)
{
  const int t  = threadIdx.x;
  const int tx = t & 15, ty = t >> 4;
  const int m0 = blockIdx.y * 128, n0 = blockIdx.x * 128;
  __shared__ float As[16][132];
  __shared__ float Bs[16][132];
  float acc[8][8];
#pragma unroll
  for (int i = 0; i < 8; ++i)
#pragma unroll
    for (int j = 0; j < 8; ++j) acc[i][j] = 0.f;

  for (int k0 = 0; k0 < K; k0 += 16) {
    const bool fullk = (k0 + 16 <= K);
#pragma unroll
    for (int i = 0; i < 2; ++i) {
      int idx = t + i * 256;
      int r  = idx >> 2;
      int kg = (idx & 3) << 2;
      const float* ap = A + (size_t)(m0 + r) * K + (k0 + kg);
      float4 v;
      if (fullk) {
        v = *reinterpret_cast<const float4*>(ap);
      } else {
        v.x = (k0 + kg + 0 < K) ? ap[0] : 0.f;
        v.y = (k0 + kg + 1 < K) ? ap[1] : 0.f;
        v.z = (k0 + kg + 2 < K) ? ap[2] : 0.f;
        v.w = (k0 + kg + 3 < K) ? ap[3] : 0.f;
      }
      As[kg + 0][r] = v.x; As[kg + 1][r] = v.y;
      As[kg + 2][r] = v.z; As[kg + 3][r] = v.w;
    }
#pragma unroll
    for (int i = 0; i < 2; ++i) {
      int idx = t + i * 256;
      int kk = idx >> 5;
      int c4 = (idx & 31) << 2;
      int gn = n0 + c4;
      float4 v = make_float4(0.f, 0.f, 0.f, 0.f);
      if (k0 + kk < K) {
        const float* bp2 = Bw + (size_t)(k0 + kk) * N + gn;
        if (gn + 3 < N) v = *reinterpret_cast<const float4*>(bp2);
        else {
          if (gn + 0 < N) v.x = bp2[0];
          if (gn + 1 < N) v.y = bp2[1];
          if (gn + 2 < N) v.z = bp2[2];
          if (gn + 3 < N) v.w = bp2[3];
        }
      }
      *reinterpret_cast<float4*>(&Bs[kk][c4]) = v;
    }
    __syncthreads();
#pragma unroll
    for (int kk = 0; kk < 16; ++kk) {
      float a[8], bfr[8];
      *reinterpret_cast<float4*>(&a[0])   = *reinterpret_cast<const float4*>(&As[kk][ty * 4]);
      *reinterpret_cast<float4*>(&a[4])   = *reinterpret_cast<const float4*>(&As[kk][64 + ty * 4]);
      *reinterpret_cast<float4*>(&bfr[0]) = *reinterpret_cast<const float4*>(&Bs[kk][tx * 4]);
      *reinterpret_cast<float4*>(&bfr[4]) = *reinterpret_cast<const float4*>(&Bs[kk][64 + tx * 4]);
#pragma unroll
      for (int i = 0; i < 8; ++i)
#pragma unroll
        for (int j = 0; j < 8; ++j)
          acc[i][j] = fmaf(a[i], bfr[j], acc[i][j]);
    }
    __syncthreads();
  }

#pragma unroll
  for (int i = 0; i < 8; ++i) {
    const int gm = m0 + ((i < 4) ? (ty * 4 + i) : (64 + ty * 4 + i - 4));
    const int srow = gm & (SS - 1);
    const size_t rowoff = (size_t)gm * N;
#pragma unroll
    for (int jh = 0; jh < 2; ++jh) {
      const int gn0 = n0 + jh * 64 + tx * 4;
      float outv[4];
#pragma unroll
      for (int c = 0; c < 4; ++c) {
        const int gn = gn0 + c;
        float v = acc[i][jh * 4 + c];
        if (gn < N) {
          if (flags & GF_BIAS)  v += bias[gn];
          if (flags & GF_RESID) v += Rz[rowoff + gn];
          if (flags & GF_POSENC) {
            float freq = expf(-(2.0f * gn / (float)DD) * 9.210340371976184f);
            float ang = (float)srow * freq;
            v += (gn & 1) ? cosf(ang) : sinf(ang);
          }
          if (flags & GF_RELU) v = fmaxf(v, 0.f);
        }
        outv[c] = v;
      }
      if (gn0 + 3 < N) {
        float4 sv; sv.x = outv[0]; sv.y = outv[1]; sv.z = outv[2]; sv.w = outv[3];
        *reinterpret_cast<float4*>(&C[rowoff + gn0]) = sv;
      } else {
#pragma unroll
        for (int c = 0; c < 4; ++c)
          if (gn0 + c < N) C[rowoff + gn0 + c] = outv[c];
      }
    }
  }
}

// ---------------------------------------------------------------------------
// Repack Wq/Wk/Wv (L,H,D,DK) -> Wt (L,D,3*D), cols [q | k | v], col=h*DK+kk
// ---------------------------------------------------------------------------
__global__ void prep_qkv(const float* __restrict__ Wq, const float* __restrict__ Wk,
                         const float* __restrict__ Wv, const float* __restrict__ bq,
                         const float* __restrict__ bk, const float* __restrict__ bv,
                         float* __restrict__ Wt, float* __restrict__ bcat)
{
  const int idx = blockIdx.x * 256 + threadIdx.x;
  const int total = LLl * HHh * DD * DKK;
  if (idx < total) {
    int kk = idx % DKK;
    int d  = (idx / DKK) % DD;
    int h  = (idx / (DKK * DD)) % HHh;
    int l  = idx / (DKK * DD * HHh);
    size_t dst = ((size_t)l * DD + d) * QKV_N;
    int col = h * DKK + kk;
    Wt[dst + col]            = Wq[idx];
    Wt[dst + DD + col]       = Wk[idx];
    Wt[dst + 2 * DD + col]   = Wv[idx];
  }
  if (idx < LLl * HHh * DKK) {
    int kk = idx % DKK;
    int h  = (idx / DKK) % HHh;
    int l  = idx / (DKK * HHh);
    int col = h * DKK + kk;
    bcat[(size_t)l * QKV_N + col]          = bq[idx];
    bcat[(size_t)l * QKV_N + DD + col]     = bk[idx];
    bcat[(size_t)l * QKV_N + 2 * DD + col] = bv[idx];
  }
}

// ---------------------------------------------------------------------------
// Flash attention, fp32. Grid: (B*H, S/64). 4 threads per q-row split the KV
// stream (slices mod 4); quad-combined via shfl_xor at the end.
// ---------------------------------------------------------------------------
__global__ __launch_bounds__(256) void attn_flash(const float* __restrict__ qkv,
                                                  float* __restrict__ o)
{
  const int bh = blockIdx.x;
  const int qt = blockIdx.y;
  const int b = bh >> 3, h = bh & 7;
  const int tid = threadIdx.x;
  const int qr  = tid >> 2;            // 0..63 q row within tile
  const int sl  = tid & 3;             // kv slice
  const int qrow = qt * 64 + qr;
  const float scale = 0.1889822365046136f;  // 1/sqrt(28)

  __shared__ float Ks[64][DKK];
  __shared__ float Vs[64][DKK];

  float qv[DKK], acc[DKK];
  {
    const float* qp = qkv + (size_t)(b * SS + qrow) * QKV_N + h * DKK;
#pragma unroll
    for (int j = 0; j < DKK; ++j) { qv[j] = qp[j] * scale; acc[j] = 0.f; }
  }
  float m = -INFINITY, l = 0.f;

  for (int tile = 0; tile <= qt; ++tile) {
    const int t0 = tile * 64;
    __syncthreads();
    for (int idx = tid; idx < 64 * DKK; idx += 256) {
      int r = idx / DKK, c = idx - r * DKK;
      const float* kp = qkv + (size_t)(b * SS + t0 + r) * QKV_N + h * DKK + c;
      Ks[r][c] = kp[DD];
      Vs[r][c] = kp[2 * DD];
    }
    __syncthreads();

    float sc[16];
    float tmax = -INFINITY;
    if (tile < qt) {
#pragma unroll
      for (int i = 0; i < 16; ++i) {
        const int r = sl + i * 4;
        float d0 = 0.f;
#pragma unroll
        for (int j = 0; j < DKK; ++j) d0 = fmaf(qv[j], Ks[r][j], d0);
        sc[i] = d0;
        tmax = fmaxf(tmax, d0);
      }
    } else {
#pragma unroll
      for (int i = 0; i < 16; ++i) {
        const int r = sl + i * 4;
        float d0 = 0.f;
#pragma unroll
        for (int j = 0; j < DKK; ++j) d0 = fmaf(qv[j], Ks[r][j], d0);
        sc[i] = (t0 + r <= qrow) ? d0 : -INFINITY;
        tmax = fmaxf(tmax, sc[i]);
      }
    }
    if (tmax > -INFINITY) {
      const float mnew = fmaxf(m, tmax);
      const float r2 = __expf(m - mnew);   // m=-inf first time -> 0
      l *= r2;
#pragma unroll
      for (int j = 0; j < DKK; ++j) acc[j] *= r2;
#pragma unroll
      for (int i = 0; i < 16; ++i) {
        const float p = __expf(sc[i] - mnew);  // masked: exp(-inf)=0
        l += p;
        const int r = sl + i * 4;
#pragma unroll
        for (int j = 0; j < DKK; ++j) acc[j] = fmaf(p, Vs[r][j], acc[j]);
      }
      m = mnew;
    }
  }

  // combine the 4 slices within the quad
  const float msave = m;
  m = fmaxf(m, __shfl_xor(m, 1));
  m = fmaxf(m, __shfl_xor(m, 2));
  const float cs = __expf(msave - m);   // slice never contributed -> 0
  l *= cs;
  l += __shfl_xor(l, 1);
  l += __shfl_xor(l, 2);
  const float inv = 1.0f / l;
  float* op = o + (size_t)(b * SS + qrow) * DD + h * DKK;
#pragma unroll
  for (int j = 0; j < DKK; ++j) {
    float a = acc[j] * cs;
    a += __shfl_xor(a, 1);
    a += __shfl_xor(a, 2);
    acc[j] = a * inv;
  }
#pragma unroll
  for (int c = 0; c < 7; ++c) op[sl * 7 + c] = acc[sl * 7 + c];
}

// ---------------------------------------------------------------------------
// LayerNorm over (S,D) per batch: partial sums (64 blocks/batch) + apply.
// ---------------------------------------------------------------------------
__global__ __launch_bounds__(256) void ln_part(const float* __restrict__ x,
                                               float* __restrict__ part)
{
  const int b = blockIdx.y, g = blockIdx.x;   // g in [0,64)
  const int tid = threadIdx.x;
  const float* xb = x + (size_t)b * SS * DD + g * 3584;
  float sum = 0.f, sq = 0.f;
  for (int i = tid * 4; i < 3584; i += 1024) {
    float4 v = *reinterpret_cast<const float4*>(&xb[i]);
    sum += v.x + v.y + v.z + v.w;
    sq  += v.x * v.x + v.y * v.y + v.z * v.z + v.w * v.w;
  }
  __shared__ float sA[4], sB[4];
#pragma unroll
  for (int o2 = 32; o2 > 0; o2 >>= 1) { sum += __shfl_down(sum, o2); sq += __shfl_down(sq, o2); }
  if ((tid & 63) == 0) { sA[tid >> 6] = sum; sB[tid >> 6] = sq; }
  __syncthreads();
  if (tid == 0) {
    part[((size_t)b * 64 + g) * 2]     = sA[0] + sA[1] + sA[2] + sA[3];
    part[((size_t)b * 64 + g) * 2 + 1] = sB[0] + sB[1] + sB[2] + sB[3];
  }
}

__global__ __launch_bounds__(256) void ln_apply(
    const float* __restrict__ x, const float* __restrict__ w, const float* __restrict__ bb,
    const float* __restrict__ part, float* __restrict__ y)
{
  const int blk = blockIdx.x;           // 896 = 224 blocks per batch * 4
  const int b = blk / 224;
  const int tid = threadIdx.x;
  __shared__ float mu_s, rstd_s;
  if (tid < 64) {
    float s1 = part[((size_t)b * 64 + tid) * 2];
    float s2 = part[((size_t)b * 64 + tid) * 2 + 1];
#pragma unroll
    for (int o2 = 32; o2 > 0; o2 >>= 1) { s1 += __shfl_down(s1, o2); s2 += __shfl_down(s2, o2); }
    if (tid == 0) {
      constexpr float NEL = (float)(SS * DD);
      float mu = s1 / NEL;
      float var = s2 / NEL - mu * mu;
      mu_s = mu;
      rstd_s = 1.0f / sqrtf(var + 1e-5f);
    }
  }
  __syncthreads();
  const float mu = mu_s, rstd = rstd_s;
  const size_t i4 = ((size_t)blk * 256 + tid) * 4;
  const size_t sd = i4 - (size_t)b * SS * DD;
  float4 xv  = *reinterpret_cast<const float4*>(&x[i4]);
  float4 wv  = *reinterpret_cast<const float4*>(&w[sd]);
  float4 bv2 = *reinterpret_cast<const float4*>(&bb[sd]);
  float4 r;
  r.x = (xv.x - mu) * rstd * wv.x + bv2.x;
  r.y = (xv.y - mu) * rstd * wv.y + bv2.y;
  r.z = (xv.z - mu) * rstd * wv.z + bv2.z;
  r.w = (xv.w - mu) * rstd * wv.w + bv2.w;
  *reinterpret_cast<float4*>(&y[i4]) = r;
}

// ---------------------------------------------------------------------------
// Row softmax over V=8000, in place on d_out.
// ---------------------------------------------------------------------------
__global__ __launch_bounds__(256) void softmax_rows(float* __restrict__ logits)
{
  const int row = blockIdx.x;
  float* p = logits + (size_t)row * VV;
  __shared__ float buf[VV];
  __shared__ float red[4];
  const int tid = threadIdx.x;

  float mx = -INFINITY;
  for (int i = tid; i < VV; i += 256) { float v = p[i]; buf[i] = v; mx = fmaxf(mx, v); }
#pragma unroll
  for (int o2 = 32; o2 > 0; o2 >>= 1) mx = fmaxf(mx, __shfl_down(mx, o2));
  if ((tid & 63) == 0) red[tid >> 6] = mx;
  __syncthreads();
  mx = fmaxf(fmaxf(red[0], red[1]), fmaxf(red[2], red[3]));
  __syncthreads();

  float s = 0.f;
  for (int i = tid; i < VV; i += 256) { float e = __expf(buf[i] - mx); buf[i] = e; s += e; }
#pragma unroll
  for (int o2 = 32; o2 > 0; o2 >>= 1) s += __shfl_down(s, o2);
  if ((tid & 63) == 0) red[tid >> 6] = s;
  __syncthreads();
  s = red[0] + red[1] + red[2] + red[3];
  const float inv = 1.0f / s;
  for (int i = tid; i < VV; i += 256) p[i] = buf[i] * inv;
}

// ---------------------------------------------------------------------------
extern "C" void kernel_launch(void* const* d_in, const int* in_sizes, int n_in,
                              void* d_out, int out_size, void* d_ws, size_t ws_size,
                              hipStream_t stream) {
  const float* x   = (const float*)d_in[0];
  const float* Wp  = (const float*)d_in[1];
  const float* bp  = (const float*)d_in[2];
  const float* Wq  = (const float*)d_in[3];
  const float* bq  = (const float*)d_in[4];
  const float* Wk  = (const float*)d_in[5];
  const float* bk  = (const float*)d_in[6];
  const float* Wv  = (const float*)d_in[7];
  const float* bv  = (const float*)d_in[8];
  const float* Wo  = (const float*)d_in[9];
  const float* bo  = (const float*)d_in[10];
  const float* W1  = (const float*)d_in[11];
  const float* b1  = (const float*)d_in[12];
  const float* W2  = (const float*)d_in[13];
  const float* b2  = (const float*)d_in[14];
  const float* W3  = (const float*)d_in[15];
  const float* b3  = (const float*)d_in[16];
  const float* lnw = (const float*)d_in[17];
  const float* lnb = (const float*)d_in[18];
  const float* Wf  = (const float*)d_in[19];
  const float* bf  = (const float*)d_in[20];

  float* ws   = (float*)d_ws;
  float* h    = ws + OFF_H;
  float* h2   = ws + OFF_H2;
  float* obuf = ws + OFF_O;
  float* wt   = ws + OFF_WT;
  float* bc   = ws + OFF_BC;
  float* qkv  = ws + OFF_BIG;
  float* f1   = ws + OFF_BIG;
  float* f2   = ws + OFF_BIG + (size_t)MT * FFF;
  float* st   = ws + OFF_ST;

  prep_qkv<<<(LLl * HHh * DD * DKK + 255) / 256, 256, 0, stream>>>(Wq, Wk, Wv, bq, bk, bv, wt, bc);

  // h = x @ Wp + bp + posenc
  gemm128<<<dim3(2, 32), 256, 0, stream>>>(x, Wp, bp, nullptr, h, DD, DIN_, GF_BIAS | GF_POSENC);

  for (int l = 0; l < LLl; ++l) {
    const float* wtl = wt + (size_t)l * DD * QKV_N;
    const float* bcl = bc + (size_t)l * QKV_N;
    gemm128<<<dim3(6, 32), 256, 0, stream>>>(h, wtl, bcl, nullptr, qkv, QKV_N, DD, GF_BIAS);
    attn_flash<<<dim3(BB * HHh, SS / 64), 256, 0, stream>>>(qkv, obuf);
    gemm128<<<dim3(2, 32), 256, 0, stream>>>(obuf, Wo + (size_t)l * DD * DD,
                                             bo + (size_t)l * DD, h, h2, DD, DD,
                                             GF_BIAS | GF_RESID);
    ln_part<<<dim3(64, BB), 256, 0, stream>>>(h2, st);
    ln_apply<<<896, 256, 0, stream>>>(h2, lnw + (size_t)l * SS * DD,
                                      lnb + (size_t)l * SS * DD, st, h);
    gemm128<<<dim3(5, 32), 256, 0, stream>>>(h, W1 + (size_t)l * DD * FFF,
                                             b1 + (size_t)l * FFF, nullptr, f1, FFF, DD,
                                             GF_BIAS | GF_RELU);
    gemm128<<<dim3(5, 32), 256, 0, stream>>>(f1, W2 + (size_t)l * FFF * FFF,
                                             b2 + (size_t)l * FFF, nullptr, f2, FFF, FFF,
                                             GF_BIAS | GF_RELU);
    gemm128<<<dim3(2, 32), 256, 0, stream>>>(f2, W3 + (size_t)l * FFF * DD,
                                             b3 + (size_t)l * DD, h, h2, DD, FFF,
                                             GF_BIAS | GF_RESID);
    ln_part<<<dim3(64, BB), 256, 0, stream>>>(h2, st);
    ln_apply<<<896, 256, 0, stream>>>(h2, lnw + (size_t)l * SS * DD,
                                      lnb + (size_t)l * SS * DD, st, h2);
    ln_part<<<dim3(64, BB), 256, 0, stream>>>(h2, st);
    ln_apply<<<896, 256, 0, stream>>>(h2, lnw + (size_t)l * SS * DD,
                                      lnb + (size_t)l * SS * DD, st, h);
  }

  gemm128<<<dim3(63, 32), 256, 0, stream>>>(h, Wf, bf, nullptr, (float*)d_out, VV, DD, GF_BIAS);
  softmax_rows<<<MT, 256, 0, stream>>>((float*)d_out);
}

// Round 3
// 1948.185 us; speedup vs baseline: 4.1897x; 2.5883x over previous
//
#include <hip/hip_runtime.h>
#include <math.h>

#define GF_BIAS   1
#define GF_RELU   2
#define GF_RESID  4
#define GF_POSENC 8
#define GF_F32OUT 16

namespace {
constexpr int BB = 4, SS = 1024, DD = 224, FFF = 600, VV = 8000, LLl = 8;
constexpr int SD = SS * DD;  // 229376

// workspace layout, bf16 element offsets
constexpr size_t WP   = 0;                         // [256][768]
constexpr size_t WQKV = WP + (size_t)256 * 768;    // L x [704][256]
constexpr size_t WO   = WQKV + (size_t)LLl * 704 * 256;
constexpr size_t W1T  = WO + (size_t)LLl * 256 * 256;
constexpr size_t W2T  = W1T + (size_t)LLl * 640 * 256;
constexpr size_t W3T  = W2T + (size_t)LLl * 640 * 640;
constexpr size_t WFT  = W3T + (size_t)LLl * 256 * 640;   // [8064][256]
constexpr size_t HB   = WFT + (size_t)8064 * 256;
constexpr size_t H2B  = HB + (size_t)4096 * 256;
constexpr size_t OBUF = H2B + (size_t)4096 * 256;
constexpr size_t BIG  = OBUF + (size_t)4096 * 256;       // xb | qkv | f1,f2
constexpr size_t ENDB = BIG + (size_t)2 * 4096 * 640;
constexpr size_t FBYTE = ENDB * 2;                       // float region byte offset
}

using short8 = __attribute__((ext_vector_type(8))) short;
using f32x4  = __attribute__((ext_vector_type(4))) float;

__device__ __forceinline__ float bits2f(unsigned u) {
  union { unsigned u; float f; } v; v.u = u; return v.f;
}
__device__ __forceinline__ unsigned short f2b(float f) {
  union { float f; unsigned u; } v; v.f = f;
  unsigned r = v.u + 0x7FFFu + ((v.u >> 16) & 1u);
  return (unsigned short)(r >> 16);
}
__device__ __forceinline__ float b2f(unsigned short b) {
  return bits2f((unsigned)b << 16);
}

// ---------------------------------------------------------------------------
// bf16 MFMA GEMM: C[M,Npad] = A[M,Kp] @ Bt[Npad,Kp]^T, epilogue fused.
// 256 thr = 4 waves (2x2), wave tile (BM/2)x(BN/2), 16x16x32 fragments.
// LDS tiles [R][64] bf16, XOR-swizzled (byte ^= (row&7)<<4), reg double-buffer.
// ---------------------------------------------------------------------------
template <int BM, int BN, int FLAGS>
__global__ __launch_bounds__(256) void gemm_mfma(
    const unsigned short* __restrict__ A, const unsigned short* __restrict__ Bt,
    const float* __restrict__ bias, const unsigned short* __restrict__ Rz,
    void* __restrict__ Cout, int Kp, int N, int ldc)
{
  constexpr int MR = BM / 32, NR = BN / 32;
  constexpr int APT = BM / 32, BPT = BN / 32;
  __shared__ __align__(16) unsigned short sA[BM * 64];
  __shared__ __align__(16) unsigned short sB[BN * 64];
  const int t = threadIdx.x;
  const int l = t & 63;
  const int w = t >> 6, wr = w >> 1, wc = w & 1;
  const int m0 = blockIdx.y * BM, n0 = blockIdx.x * BN;
  const int nk = Kp >> 6;

  int aoff[APT], ar[APT], ac[APT];
#pragma unroll
  for (int p = 0; p < APT; ++p) {
    int off = (t + p * 256) * 16;
    int r = off >> 7;
    int cb = (off & 127) ^ ((r & 7) << 4);
    aoff[p] = off; ar[p] = r; ac[p] = cb >> 1;
  }
  int boff[BPT], br[BPT], bc[BPT];
#pragma unroll
  for (int p = 0; p < BPT; ++p) {
    int off = (t + p * 256) * 16;
    int r = off >> 7;
    int cb = (off & 127) ^ ((r & 7) << 4);
    boff[p] = off; br[p] = r; bc[p] = cb >> 1;
  }

  const unsigned short* Ab = A + (size_t)m0 * Kp;
  const unsigned short* Bb = Bt + (size_t)n0 * Kp;

  uint4 ra[APT], rb[BPT];
#pragma unroll
  for (int p = 0; p < APT; ++p) ra[p] = *(const uint4*)(Ab + (size_t)ar[p] * Kp + ac[p]);
#pragma unroll
  for (int p = 0; p < BPT; ++p) rb[p] = *(const uint4*)(Bb + (size_t)br[p] * Kp + bc[p]);

  f32x4 acc[MR][NR];
#pragma unroll
  for (int i = 0; i < MR; ++i)
#pragma unroll
    for (int j = 0; j < NR; ++j) acc[i][j] = {0.f, 0.f, 0.f, 0.f};

  for (int kt = 0; kt < nk; ++kt) {
#pragma unroll
    for (int p = 0; p < APT; ++p) *(uint4*)((char*)sA + aoff[p]) = ra[p];
#pragma unroll
    for (int p = 0; p < BPT; ++p) *(uint4*)((char*)sB + boff[p]) = rb[p];
    __syncthreads();
    if (kt + 1 < nk) {
      const int k1 = (kt + 1) * 64;
#pragma unroll
      for (int p = 0; p < APT; ++p) ra[p] = *(const uint4*)(Ab + (size_t)ar[p] * Kp + k1 + ac[p]);
#pragma unroll
      for (int p = 0; p < BPT; ++p) rb[p] = *(const uint4*)(Bb + (size_t)br[p] * Kp + k1 + bc[p]);
    }
#pragma unroll
    for (int kh = 0; kh < 2; ++kh) {
      short8 af[MR], bfg[NR];
#pragma unroll
      for (int mi = 0; mi < MR; ++mi) {
        const int row = wr * (BM / 2) + mi * 16 + (l & 15);
        const int byte = (row * 128 + kh * 64 + (l >> 4) * 16) ^ ((row & 7) << 4);
        af[mi] = *(const short8*)((const char*)sA + byte);
      }
#pragma unroll
      for (int ni = 0; ni < NR; ++ni) {
        const int row = wc * (BN / 2) + ni * 16 + (l & 15);
        const int byte = (row * 128 + kh * 64 + (l >> 4) * 16) ^ ((row & 7) << 4);
        bfg[ni] = *(const short8*)((const char*)sB + byte);
      }
#pragma unroll
      for (int mi = 0; mi < MR; ++mi)
#pragma unroll
        for (int ni = 0; ni < NR; ++ni)
          acc[mi][ni] = __builtin_amdgcn_mfma_f32_16x16x32_bf16(af[mi], bfg[ni], acc[mi][ni], 0, 0, 0);
    }
    __syncthreads();
  }

  const int cl = l & 15, rl0 = (l >> 4) * 4;
#pragma unroll
  for (int mi = 0; mi < MR; ++mi) {
#pragma unroll
    for (int ni = 0; ni < NR; ++ni) {
#pragma unroll
      for (int j = 0; j < 4; ++j) {
        const int gm = m0 + wr * (BM / 2) + mi * 16 + rl0 + j;
        const int gn = n0 + wc * (BN / 2) + ni * 16 + cl;
        float v = acc[mi][ni][j];
        if ((FLAGS & GF_BIAS) && gn < N) v += bias[gn];
        if (FLAGS & GF_RESID) v += b2f(Rz[(size_t)gm * ldc + gn]);
        if ((FLAGS & GF_POSENC) && gn < N) {
          const int srow = gm & (SS - 1);
          float freq = expf(-(2.0f * gn / 224.0f) * 9.210340371976184f);
          float ang = (float)srow * freq;
          v += (gn & 1) ? cosf(ang) : sinf(ang);
        }
        if (FLAGS & GF_RELU) v = fmaxf(v, 0.f);
        if (FLAGS & GF_F32OUT) {
          if (gn < N) ((float*)Cout)[(size_t)gm * ldc + gn] = v;
        } else {
          ((unsigned short*)Cout)[(size_t)gm * ldc + gn] = f2b(v);
        }
      }
    }
  }
}

// ---------------------------------------------------------------------------
// Weight prep: fp32 [K][N] (xL) -> bf16 transposed padded [Np][Kp] (xL)
// ---------------------------------------------------------------------------
__global__ void prep_wt(const float* __restrict__ W, unsigned short* __restrict__ O,
                        int K, int N, int Kp, int Np, size_t sW, size_t sO)
{
  const int ll = blockIdx.y;
  const size_t id = (size_t)blockIdx.x * 256 + threadIdx.x;
  const int k = (int)(id % Kp);
  const int n = (int)(id / Kp);
  float v = 0.f;
  if (n < N && k < K) v = W[sW * ll + (size_t)k * N + n];
  O[sO * ll + id] = f2b(v);
}

__global__ void prep_wqkv(const float* __restrict__ Wq, const float* __restrict__ Wk,
                          const float* __restrict__ Wv, const float* __restrict__ bq,
                          const float* __restrict__ bk, const float* __restrict__ bv,
                          unsigned short* __restrict__ O, float* __restrict__ bcat)
{
  const int ll = blockIdx.y;
  const int id = blockIdx.x * 256 + threadIdx.x;   // < 704*256
  const int k = id & 255;
  const int n = id >> 8;
  float v = 0.f;
  if (n < 672 && k < 224) {
    const int which = n / 224, colin = n % 224;
    const int h = colin / 28, kk = colin % 28;
    const float* src = which == 0 ? Wq : (which == 1 ? Wk : Wv);
    v = src[(((size_t)ll * 8 + h) * 224 + k) * 28 + kk];
  }
  O[(size_t)ll * (704 * 256) + (size_t)n * 256 + k] = f2b(v);
  if (id < 672) {
    const int which = id / 224, colin = id % 224;
    const int h = colin / 28, kk = colin % 28;
    const float* src = which == 0 ? bq : (which == 1 ? bk : bv);
    bcat[ll * 672 + id] = src[((size_t)ll * 8 + h) * 28 + kk];
  }
}

__global__ void prep_x(const float* __restrict__ x, unsigned short* __restrict__ xb)
{
  const size_t i = ((size_t)blockIdx.x * 256 + threadIdx.x) * 4;
  float4 v = *(const float4*)(x + i);
  ushort4 o;
  o.x = f2b(v.x); o.y = f2b(v.y); o.z = f2b(v.z); o.w = f2b(v.w);
  *(ushort4*)(xb + i) = o;
}

// ---------------------------------------------------------------------------
// Flash attention, fp32 math on bf16 tensors. Grid: (B*H, S/64).
// qkv stride 704: q @ h*28, k @ 224+h*28, v @ 448+h*28. 4 kv-slices/q-row.
// ---------------------------------------------------------------------------
__global__ __launch_bounds__(256) void attn_flash(const unsigned short* __restrict__ qkv,
                                                  unsigned short* __restrict__ o)
{
  const int bh = blockIdx.x, qt = blockIdx.y;
  const int b = bh >> 3, h = bh & 7;
  const int tid = threadIdx.x;
  const int qr = tid >> 2, sl = tid & 3;
  const int qrow = qt * 64 + qr;
  const float scale = 0.1889822365046136f;  // 1/sqrt(28)

  __shared__ float Ks[64][28];
  __shared__ float Vs[64][28];

  float qv[28], acc[28];
  {
    const unsigned short* qp = qkv + ((size_t)(b * SS + qrow)) * 704 + h * 28;
#pragma unroll
    for (int c4 = 0; c4 < 7; ++c4) {
      ushort4 u = *(const ushort4*)(qp + c4 * 4);
      qv[c4 * 4 + 0] = b2f(u.x) * scale;
      qv[c4 * 4 + 1] = b2f(u.y) * scale;
      qv[c4 * 4 + 2] = b2f(u.z) * scale;
      qv[c4 * 4 + 3] = b2f(u.w) * scale;
    }
#pragma unroll
    for (int j = 0; j < 28; ++j) acc[j] = 0.f;
  }
  float m = -INFINITY, l = 0.f;

  for (int tile = 0; tile <= qt; ++tile) {
    const int t0 = tile * 64;
    __syncthreads();
    for (int idx = tid; idx < 448; idx += 256) {
      const int r = idx / 7, c4 = idx % 7;
      const unsigned short* kp = qkv + ((size_t)(b * SS + t0 + r)) * 704 + 224 + h * 28 + c4 * 4;
      ushort4 ku = *(const ushort4*)kp;
      ushort4 vu = *(const ushort4*)(kp + 224);
      Ks[r][c4 * 4 + 0] = b2f(ku.x); Ks[r][c4 * 4 + 1] = b2f(ku.y);
      Ks[r][c4 * 4 + 2] = b2f(ku.z); Ks[r][c4 * 4 + 3] = b2f(ku.w);
      Vs[r][c4 * 4 + 0] = b2f(vu.x); Vs[r][c4 * 4 + 1] = b2f(vu.y);
      Vs[r][c4 * 4 + 2] = b2f(vu.z); Vs[r][c4 * 4 + 3] = b2f(vu.w);
    }
    __syncthreads();

    float sc[16];
    float tmax = -INFINITY;
    if (tile < qt) {
#pragma unroll
      for (int i = 0; i < 16; ++i) {
        const int r = sl + i * 4;
        float d0 = 0.f;
#pragma unroll
        for (int j = 0; j < 28; ++j) d0 = fmaf(qv[j], Ks[r][j], d0);
        sc[i] = d0;
        tmax = fmaxf(tmax, d0);
      }
    } else {
#pragma unroll
      for (int i = 0; i < 16; ++i) {
        const int r = sl + i * 4;
        float d0 = 0.f;
#pragma unroll
        for (int j = 0; j < 28; ++j) d0 = fmaf(qv[j], Ks[r][j], d0);
        sc[i] = (t0 + r <= qrow) ? d0 : -INFINITY;
        tmax = fmaxf(tmax, sc[i]);
      }
    }
    if (tmax > -INFINITY) {
      const float mnew = fmaxf(m, tmax);
      const float r2 = __expf(m - mnew);
      l *= r2;
#pragma unroll
      for (int j = 0; j < 28; ++j) acc[j] *= r2;
#pragma unroll
      for (int i = 0; i < 16; ++i) {
        const float p = __expf(sc[i] - mnew);
        l += p;
        const int r = sl + i * 4;
#pragma unroll
        for (int j = 0; j < 28; ++j) acc[j] = fmaf(p, Vs[r][j], acc[j]);
      }
      m = mnew;
    }
  }

  const float msave = m;
  m = fmaxf(m, __shfl_xor(m, 1));
  m = fmaxf(m, __shfl_xor(m, 2));
  const float cs = __expf(msave - m);
  l *= cs;
  l += __shfl_xor(l, 1);
  l += __shfl_xor(l, 2);
  const float inv = 1.0f / l;
  unsigned short* op = o + ((size_t)(b * SS + qrow)) * 256 + h * 28;
#pragma unroll
  for (int j = 0; j < 28; ++j) {
    float a = acc[j] * cs;
    a += __shfl_xor(a, 1);
    a += __shfl_xor(a, 2);
    acc[j] = a * inv;
  }
#pragma unroll
  for (int c = 0; c < 7; ++c) op[sl * 7 + c] = f2b(acc[sl * 7 + c]);
}

// ---------------------------------------------------------------------------
// LayerNorm over (S,D) per batch, bf16 tensors (stride 256, 224 real cols).
// ---------------------------------------------------------------------------
__device__ __forceinline__ void reduce_stats(const float* __restrict__ part, int b,
                                             float& mu, float& rstd, float* sh)
{
  const int tid = threadIdx.x;
  if (tid < 64) {
    float s1 = part[((size_t)b * 64 + tid) * 2];
    float s2 = part[((size_t)b * 64 + tid) * 2 + 1];
#pragma unroll
    for (int o2 = 32; o2 > 0; o2 >>= 1) { s1 += __shfl_down(s1, o2); s2 += __shfl_down(s2, o2); }
    if (tid == 0) {
      float m = s1 / (float)SD;
      float var = s2 / (float)SD - m * m;
      sh[0] = m; sh[1] = 1.0f / sqrtf(var + 1e-5f);
    }
  }
  __syncthreads();
  mu = sh[0]; rstd = sh[1];
}

__global__ __launch_bounds__(256) void ln_part(const unsigned short* __restrict__ x,
                                               float* __restrict__ part)
{
  const int b = blockIdx.y, g = blockIdx.x;
  const unsigned short* base = x + ((size_t)b * 1024 + g * 16) * 256;
  float sum = 0.f, sq = 0.f;
  for (int c = threadIdx.x; c < 448; c += 256) {
    const int r = c / 28, cc = c % 28;
    uint4 u = *(const uint4*)(base + (size_t)r * 256 + cc * 8);
    const unsigned* up = (const unsigned*)&u;
#pragma unroll
    for (int q = 0; q < 4; ++q) {
      float f0 = bits2f(up[q] << 16);
      float f1 = bits2f(up[q] & 0xFFFF0000u);
      sum += f0 + f1; sq += f0 * f0 + f1 * f1;
    }
  }
  __shared__ float sA[4], sB[4];
#pragma unroll
  for (int o2 = 32; o2 > 0; o2 >>= 1) { sum += __shfl_down(sum, o2); sq += __shfl_down(sq, o2); }
  if ((threadIdx.x & 63) == 0) { sA[threadIdx.x >> 6] = sum; sB[threadIdx.x >> 6] = sq; }
  __syncthreads();
  if (threadIdx.x == 0) {
    part[((size_t)b * 64 + g) * 2] = sA[0] + sA[1] + sA[2] + sA[3];
    part[((size_t)b * 64 + g) * 2 + 1] = sB[0] + sB[1] + sB[2] + sB[3];
  }
}

__global__ __launch_bounds__(256) void ln_apply(
    const unsigned short* __restrict__ x, const float* __restrict__ w,
    const float* __restrict__ bb, const float* __restrict__ part,
    unsigned short* __restrict__ y)
{
  __shared__ float sh[2];
  const int b = blockIdx.x / 112;
  float mu, rstd;
  reduce_stats(part, b, mu, rstd, sh);
  const int chunk = blockIdx.x * 256 + threadIdx.x;
  const int r = chunk / 28, cc = chunk % 28;
  const int s = r & 1023;
  uint4 u = *(const uint4*)(x + (size_t)r * 256 + cc * 8);
  const float* wp = w + (size_t)s * 224 + cc * 8;
  const float* bp = bb + (size_t)s * 224 + cc * 8;
  float4 w0 = *(const float4*)wp, w1 = *(const float4*)(wp + 4);
  float4 b0 = *(const float4*)bp, b1 = *(const float4*)(bp + 4);
  const float* wf = (const float*)&w0;  // w0,w1 contiguous? keep explicit:
  float wv[8] = {w0.x, w0.y, w0.z, w0.w, w1.x, w1.y, w1.z, w1.w};
  float bv[8] = {b0.x, b0.y, b0.z, b0.w, b1.x, b1.y, b1.z, b1.w};
  (void)wf;
  const unsigned* up = (const unsigned*)&u;
  uint4 ov;
  unsigned* op = (unsigned*)&ov;
#pragma unroll
  for (int q = 0; q < 4; ++q) {
    float f0 = bits2f(up[q] << 16), f1 = bits2f(up[q] & 0xFFFF0000u);
    float y0 = (f0 - mu) * rstd * wv[q * 2] + bv[q * 2];
    float y1 = (f1 - mu) * rstd * wv[q * 2 + 1] + bv[q * 2 + 1];
    op[q] = (unsigned)f2b(y0) | ((unsigned)f2b(y1) << 16);
  }
  *(uint4*)(y + (size_t)r * 256 + cc * 8) = ov;
}

__global__ __launch_bounds__(256) void ln_part2(
    const unsigned short* __restrict__ x, const float* __restrict__ w,
    const float* __restrict__ bb, const float* __restrict__ part,
    float* __restrict__ part2)
{
  __shared__ float sh[2];
  const int b = blockIdx.y, g = blockIdx.x;
  float mu, rstd;
  reduce_stats(part, b, mu, rstd, sh);
  const unsigned short* base = x + ((size_t)b * 1024 + g * 16) * 256;
  float sum = 0.f, sq = 0.f;
  for (int c = threadIdx.x; c < 448; c += 256) {
    const int r = c / 28, cc = c % 28;
    const int s = g * 16 + r;
    uint4 u = *(const uint4*)(base + (size_t)r * 256 + cc * 8);
    const float* wp = w + (size_t)s * 224 + cc * 8;
    const float* bp = bb + (size_t)s * 224 + cc * 8;
    float4 w0 = *(const float4*)wp, w1 = *(const float4*)(wp + 4);
    float4 b0 = *(const float4*)bp, b1 = *(const float4*)(bp + 4);
    float wv[8] = {w0.x, w0.y, w0.z, w0.w, w1.x, w1.y, w1.z, w1.w};
    float bv[8] = {b0.x, b0.y, b0.z, b0.w, b1.x, b1.y, b1.z, b1.w};
    const unsigned* up = (const unsigned*)&u;
#pragma unroll
    for (int q = 0; q < 4; ++q) {
      float f0 = bits2f(up[q] << 16), f1 = bits2f(up[q] & 0xFFFF0000u);
      float y0 = (f0 - mu) * rstd * wv[q * 2] + bv[q * 2];
      float y1 = (f1 - mu) * rstd * wv[q * 2 + 1] + bv[q * 2 + 1];
      sum += y0 + y1; sq += y0 * y0 + y1 * y1;
    }
  }
  __shared__ float sA[4], sB[4];
#pragma unroll
  for (int o2 = 32; o2 > 0; o2 >>= 1) { sum += __shfl_down(sum, o2); sq += __shfl_down(sq, o2); }
  if ((threadIdx.x & 63) == 0) { sA[threadIdx.x >> 6] = sum; sB[threadIdx.x >> 6] = sq; }
  __syncthreads();
  if (threadIdx.x == 0) {
    part2[((size_t)b * 64 + g) * 2] = sA[0] + sA[1] + sA[2] + sA[3];
    part2[((size_t)b * 64 + g) * 2 + 1] = sB[0] + sB[1] + sB[2] + sB[3];
  }
}

__global__ __launch_bounds__(256) void ln_apply2(
    const unsigned short* __restrict__ x, const float* __restrict__ w,
    const float* __restrict__ bb, const float* __restrict__ part,
    const float* __restrict__ part2, unsigned short* __restrict__ y)
{
  __shared__ float sh[4];
  const int tid = threadIdx.x;
  const int b = blockIdx.x / 112;
  if (tid < 64) {
    float s1 = part[((size_t)b * 64 + tid) * 2];
    float s2 = part[((size_t)b * 64 + tid) * 2 + 1];
#pragma unroll
    for (int o2 = 32; o2 > 0; o2 >>= 1) { s1 += __shfl_down(s1, o2); s2 += __shfl_down(s2, o2); }
    if (tid == 0) {
      float m = s1 / (float)SD;
      sh[0] = m; sh[1] = 1.0f / sqrtf(s2 / (float)SD - m * m + 1e-5f);
    }
  } else if (tid < 128) {
    const int u2 = tid - 64;
    float s1 = part2[((size_t)b * 64 + u2) * 2];
    float s2 = part2[((size_t)b * 64 + u2) * 2 + 1];
#pragma unroll
    for (int o2 = 32; o2 > 0; o2 >>= 1) { s1 += __shfl_down(s1, o2); s2 += __shfl_down(s2, o2); }
    if (u2 == 0) {
      float m = s1 / (float)SD;
      sh[2] = m; sh[3] = 1.0f / sqrtf(s2 / (float)SD - m * m + 1e-5f);
    }
  }
  __syncthreads();
  const float mu1 = sh[0], rs1 = sh[1], mu2 = sh[2], rs2 = sh[3];
  const int chunk = blockIdx.x * 256 + tid;
  const int r = chunk / 28, cc = chunk % 28;
  const int s = r & 1023;
  uint4 u = *(const uint4*)(x + (size_t)r * 256 + cc * 8);
  const float* wp = w + (size_t)s * 224 + cc * 8;
  const float* bp = bb + (size_t)s * 224 + cc * 8;
  float4 w0 = *(const float4*)wp, w1 = *(const float4*)(wp + 4);
  float4 b0 = *(const float4*)bp, b1 = *(const float4*)(bp + 4);
  float wv[8] = {w0.x, w0.y, w0.z, w0.w, w1.x, w1.y, w1.z, w1.w};
  float bv[8] = {b0.x, b0.y, b0.z, b0.w, b1.x, b1.y, b1.z, b1.w};
  const unsigned* up = (const unsigned*)&u;
  uint4 ov;
  unsigned* op = (unsigned*)&ov;
#pragma unroll
  for (int q = 0; q < 4; ++q) {
    float f0 = bits2f(up[q] << 16), f1 = bits2f(up[q] & 0xFFFF0000u);
    float y0 = (f0 - mu1) * rs1 * wv[q * 2] + bv[q * 2];
    float y1 = (f1 - mu1) * rs1 * wv[q * 2 + 1] + bv[q * 2 + 1];
    float z0 = (y0 - mu2) * rs2 * wv[q * 2] + bv[q * 2];
    float z1 = (y1 - mu2) * rs2 * wv[q * 2 + 1] + bv[q * 2 + 1];
    op[q] = (unsigned)f2b(z0) | ((unsigned)f2b(z1) << 16);
  }
  *(uint4*)(y + (size_t)r * 256 + cc * 8) = ov;
}

// ---------------------------------------------------------------------------
// Row softmax over V=8000, in place on d_out (fp32).
// ---------------------------------------------------------------------------
__global__ __launch_bounds__(256) void softmax_rows(float* __restrict__ logits)
{
  const int row = blockIdx.x;
  float* p = logits + (size_t)row * VV;
  __shared__ float buf[VV];
  __shared__ float red[4];
  const int tid = threadIdx.x;

  float mx = -INFINITY;
  for (int i = tid; i < VV; i += 256) { float v = p[i]; buf[i] = v; mx = fmaxf(mx, v); }
#pragma unroll
  for (int o2 = 32; o2 > 0; o2 >>= 1) mx = fmaxf(mx, __shfl_down(mx, o2));
  if ((tid & 63) == 0) red[tid >> 6] = mx;
  __syncthreads();
  mx = fmaxf(fmaxf(red[0], red[1]), fmaxf(red[2], red[3]));
  __syncthreads();

  float s = 0.f;
  for (int i = tid; i < VV; i += 256) { float e = __expf(buf[i] - mx); buf[i] = e; s += e; }
#pragma unroll
  for (int o2 = 32; o2 > 0; o2 >>= 1) s += __shfl_down(s, o2);
  if ((tid & 63) == 0) red[tid >> 6] = s;
  __syncthreads();
  s = red[0] + red[1] + red[2] + red[3];
  const float inv = 1.0f / s;
  for (int i = tid; i < VV; i += 256) p[i] = buf[i] * inv;
}

// ---------------------------------------------------------------------------
extern "C" void kernel_launch(void* const* d_in, const int* in_sizes, int n_in,
                              void* d_out, int out_size, void* d_ws, size_t ws_size,
                              hipStream_t stream) {
  const float* x   = (const float*)d_in[0];
  const float* Wp  = (const float*)d_in[1];
  const float* bp  = (const float*)d_in[2];
  const float* Wq  = (const float*)d_in[3];
  const float* bq  = (const float*)d_in[4];
  const float* Wk  = (const float*)d_in[5];
  const float* bk  = (const float*)d_in[6];
  const float* Wv  = (const float*)d_in[7];
  const float* bv  = (const float*)d_in[8];
  const float* Wo  = (const float*)d_in[9];
  const float* bo  = (const float*)d_in[10];
  const float* W1  = (const float*)d_in[11];
  const float* b1  = (const float*)d_in[12];
  const float* W2  = (const float*)d_in[13];
  const float* b2  = (const float*)d_in[14];
  const float* W3  = (const float*)d_in[15];
  const float* b3  = (const float*)d_in[16];
  const float* lnw = (const float*)d_in[17];
  const float* lnb = (const float*)d_in[18];
  const float* Wf  = (const float*)d_in[19];
  const float* bf  = (const float*)d_in[20];

  unsigned short* wsb = (unsigned short*)d_ws;
  unsigned short* wpT   = wsb + WP;
  unsigned short* wqkvT = wsb + WQKV;
  unsigned short* woT   = wsb + WO;
  unsigned short* w1T   = wsb + W1T;
  unsigned short* w2T   = wsb + W2T;
  unsigned short* w3T   = wsb + W3T;
  unsigned short* wfT   = wsb + WFT;
  unsigned short* h     = wsb + HB;
  unsigned short* h2    = wsb + H2B;
  unsigned short* obuf  = wsb + OBUF;
  unsigned short* xb    = wsb + BIG;
  unsigned short* qkvb  = wsb + BIG;
  unsigned short* f1    = wsb + BIG;
  unsigned short* f2    = wsb + BIG + (size_t)4096 * 640;
  float* bcat  = (float*)((char*)d_ws + FBYTE);
  float* part  = bcat + LLl * 672;
  float* part2 = part + 512;

  // ---- prep (bf16 casts / transposes) ----
  prep_x<<<3072, 256, 0, stream>>>(x, xb);
  prep_wt<<<dim3(768, 1), 256, 0, stream>>>(Wp, wpT, 768, 224, 768, 256, 0, 0);
  prep_wqkv<<<dim3(704, 8), 256, 0, stream>>>(Wq, Wk, Wv, bq, bk, bv, wqkvT, bcat);
  prep_wt<<<dim3(256, 8), 256, 0, stream>>>(Wo, woT, 224, 224, 256, 256,
                                            (size_t)224 * 224, (size_t)256 * 256);
  prep_wt<<<dim3(640, 8), 256, 0, stream>>>(W1, w1T, 224, 600, 256, 640,
                                            (size_t)224 * 600, (size_t)640 * 256);
  prep_wt<<<dim3(1600, 8), 256, 0, stream>>>(W2, w2T, 600, 600, 640, 640,
                                             (size_t)600 * 600, (size_t)640 * 640);
  prep_wt<<<dim3(640, 8), 256, 0, stream>>>(W3, w3T, 600, 224, 640, 256,
                                            (size_t)600 * 224, (size_t)256 * 640);
  prep_wt<<<dim3(8064, 1), 256, 0, stream>>>(Wf, wfT, 224, 8000, 256, 8064, 0, 0);

  // ---- proj + posenc: h = x @ Wp + bp + pe ----
  gemm_mfma<64, 64, GF_BIAS | GF_POSENC><<<dim3(4, 64), 256, 0, stream>>>(
      xb, wpT, bp, nullptr, h, 768, 224, 256);

  for (int l = 0; l < LLl; ++l) {
    gemm_mfma<64, 64, GF_BIAS><<<dim3(11, 64), 256, 0, stream>>>(
        h, wqkvT + (size_t)l * 704 * 256, bcat + l * 672, nullptr, qkvb, 256, 672, 704);
    attn_flash<<<dim3(BB * 8, SS / 64), 256, 0, stream>>>(qkvb, obuf);
    gemm_mfma<64, 64, GF_BIAS | GF_RESID><<<dim3(4, 64), 256, 0, stream>>>(
        obuf, woT + (size_t)l * 256 * 256, bo + (size_t)l * 224, h, h2, 256, 224, 256);
    ln_part<<<dim3(64, BB), 256, 0, stream>>>(h2, part);
    ln_apply<<<448, 256, 0, stream>>>(h2, lnw + (size_t)l * SD, lnb + (size_t)l * SD, part, h);
    gemm_mfma<64, 64, GF_BIAS | GF_RELU><<<dim3(10, 64), 256, 0, stream>>>(
        h, w1T + (size_t)l * 640 * 256, b1 + (size_t)l * 600, nullptr, f1, 256, 600, 640);
    gemm_mfma<64, 64, GF_BIAS | GF_RELU><<<dim3(10, 64), 256, 0, stream>>>(
        f1, w2T + (size_t)l * 640 * 640, b2 + (size_t)l * 600, nullptr, f2, 640, 600, 640);
    gemm_mfma<64, 64, GF_BIAS | GF_RESID><<<dim3(4, 64), 256, 0, stream>>>(
        f2, w3T + (size_t)l * 256 * 640, b3 + (size_t)l * 224, h, h2, 640, 224, 256);
    ln_part<<<dim3(64, BB), 256, 0, stream>>>(h2, part);
    ln_part2<<<dim3(64, BB), 256, 0, stream>>>(h2, lnw + (size_t)l * SD, lnb + (size_t)l * SD,
                                               part, part2);
    ln_apply2<<<448, 256, 0, stream>>>(h2, lnw + (size_t)l * SD, lnb + (size_t)l * SD,
                                       part, part2, h);
  }

  // ---- logits (fp32 out) + softmax ----
  gemm_mfma<128, 128, GF_BIAS | GF_F32OUT><<<dim3(63, 32), 256, 0, stream>>>(
      h, wfT, bf, nullptr, (float*)d_out, 256, 8000, 8000);
  softmax_rows<<<4096, 256, 0, stream>>>((float*)d_out);
}

// Round 4
// 1660.778 us; speedup vs baseline: 4.9147x; 1.1731x over previous
//
#include <hip/hip_runtime.h>
#include <math.h>

#define GF_BIAS   1
#define GF_RELU   2
#define GF_RESID  4
#define GF_POSENC 8
#define GF_F32OUT 16
#define GF_STAT   32
#define GF_SWAP   64

namespace {
constexpr int BB = 4, SS = 1024, DD = 224, FFF = 600, VV = 8000, LLl = 8;
constexpr int SD = SS * DD;  // 229376

// workspace layout, bf16 element offsets
constexpr size_t WP   = 0;                         // [256][768]
constexpr size_t WQKV = WP + (size_t)256 * 768;    // L x [704][256]
constexpr size_t WO   = WQKV + (size_t)LLl * 704 * 256;
constexpr size_t W1T  = WO + (size_t)LLl * 256 * 256;
constexpr size_t W2T  = W1T + (size_t)LLl * 640 * 256;
constexpr size_t W3T  = W2T + (size_t)LLl * 640 * 640;
constexpr size_t WFT  = W3T + (size_t)LLl * 256 * 640;   // [8064][256]
constexpr size_t HB   = WFT + (size_t)8064 * 256;
constexpr size_t H2B  = HB + (size_t)4096 * 256;
constexpr size_t OBUF = H2B + (size_t)4096 * 256;
constexpr size_t BIG  = OBUF + (size_t)4096 * 256;       // xb | qkv | f1,f2
constexpr size_t ENDB = BIG + (size_t)2 * 4096 * 640;
constexpr size_t FBYTE = ENDB * 2;                       // float region byte offset
}

using short8 = __attribute__((ext_vector_type(8))) short;
using f32x4  = __attribute__((ext_vector_type(4))) float;

__device__ __forceinline__ float bits2f(unsigned u) {
  union { unsigned u; float f; } v; v.u = u; return v.f;
}
__device__ __forceinline__ unsigned short f2b(float f) {
  union { float f; unsigned u; } v; v.f = f;
  unsigned r = v.u + 0x7FFFu + ((v.u >> 16) & 1u);
  return (unsigned short)(r >> 16);
}
__device__ __forceinline__ float b2f(unsigned short b) {
  return bits2f((unsigned)b << 16);
}

// ---------------------------------------------------------------------------
// bf16 MFMA GEMM: C[M,Npad] = A[M,Kp] @ Bt[Npad,Kp]^T, epilogue fused.
// 256 thr = 4 waves (2x2), 16x16x32 fragments. LDS tiles [R][64] bf16,
// XOR-swizzled, reg double-buffer. C written via LDS stage -> coalesced rows.
// ---------------------------------------------------------------------------
template <int BM, int BN, int FLAGS>
__global__ __launch_bounds__(256) void gemm_mfma(
    const unsigned short* __restrict__ A, const unsigned short* __restrict__ Bt,
    const float* __restrict__ bias, const unsigned short* __restrict__ Rz,
    void* __restrict__ Cout, int Kp, int N, int ldc, float* __restrict__ statOut)
{
  constexpr int MR = BM / 32, NR = BN / 32;
  constexpr int APT = BM / 32, BPT = BN / 32;
  constexpr int ABY = BM * 128, BBY = BN * 128;   // bytes
  constexpr int CBY = (FLAGS & GF_F32OUT) ? (64 * (BN + 4) * 4) : (BM * (BN + 8) * 2);
  constexpr int SBY = (ABY + BBY) > CBY ? (ABY + BBY) : CBY;
  __shared__ __align__(16) char smem[SBY];
  __shared__ float red[8];
  unsigned short* sA = (unsigned short*)smem;
  unsigned short* sB = (unsigned short*)(smem + ABY);
  const int t = threadIdx.x;
  const int l = t & 63;
  const int w = t >> 6, wr = w >> 1, wc = w & 1;
  const int m0 = ((FLAGS & GF_SWAP) ? blockIdx.x : blockIdx.y) * BM;
  const int n0 = ((FLAGS & GF_SWAP) ? blockIdx.y : blockIdx.x) * BN;
  const int nk = Kp >> 6;

  int aoff[APT], ar[APT], ac[APT];
#pragma unroll
  for (int p = 0; p < APT; ++p) {
    int off = (t + p * 256) * 16;
    int r = off >> 7;
    int cb = (off & 127) ^ ((r & 7) << 4);
    aoff[p] = off; ar[p] = r; ac[p] = cb >> 1;
  }
  int boff[BPT], br[BPT], bc[BPT];
#pragma unroll
  for (int p = 0; p < BPT; ++p) {
    int off = (t + p * 256) * 16;
    int r = off >> 7;
    int cb = (off & 127) ^ ((r & 7) << 4);
    boff[p] = off; br[p] = r; bc[p] = cb >> 1;
  }

  const unsigned short* Ab = A + (size_t)m0 * Kp;
  const unsigned short* Bb = Bt + (size_t)n0 * Kp;

  uint4 ra[APT], rb[BPT];
#pragma unroll
  for (int p = 0; p < APT; ++p) ra[p] = *(const uint4*)(Ab + (size_t)ar[p] * Kp + ac[p]);
#pragma unroll
  for (int p = 0; p < BPT; ++p) rb[p] = *(const uint4*)(Bb + (size_t)br[p] * Kp + bc[p]);

  f32x4 acc[MR][NR];
#pragma unroll
  for (int i = 0; i < MR; ++i)
#pragma unroll
    for (int j = 0; j < NR; ++j) acc[i][j] = {0.f, 0.f, 0.f, 0.f};

  for (int kt = 0; kt < nk; ++kt) {
#pragma unroll
    for (int p = 0; p < APT; ++p) *(uint4*)((char*)sA + aoff[p]) = ra[p];
#pragma unroll
    for (int p = 0; p < BPT; ++p) *(uint4*)((char*)sB + boff[p]) = rb[p];
    __syncthreads();
    if (kt + 1 < nk) {
      const int k1 = (kt + 1) * 64;
#pragma unroll
      for (int p = 0; p < APT; ++p) ra[p] = *(const uint4*)(Ab + (size_t)ar[p] * Kp + k1 + ac[p]);
#pragma unroll
      for (int p = 0; p < BPT; ++p) rb[p] = *(const uint4*)(Bb + (size_t)br[p] * Kp + k1 + bc[p]);
    }
#pragma unroll
    for (int kh = 0; kh < 2; ++kh) {
      short8 af[MR], bfg[NR];
#pragma unroll
      for (int mi = 0; mi < MR; ++mi) {
        const int row = wr * (BM / 2) + mi * 16 + (l & 15);
        const int byte = (row * 128 + kh * 64 + (l >> 4) * 16) ^ ((row & 7) << 4);
        af[mi] = *(const short8*)((const char*)sA + byte);
      }
#pragma unroll
      for (int ni = 0; ni < NR; ++ni) {
        const int row = wc * (BN / 2) + ni * 16 + (l & 15);
        const int byte = (row * 128 + kh * 64 + (l >> 4) * 16) ^ ((row & 7) << 4);
        bfg[ni] = *(const short8*)((const char*)sB + byte);
      }
#pragma unroll
      for (int mi = 0; mi < MR; ++mi)
#pragma unroll
        for (int ni = 0; ni < NR; ++ni)
          acc[mi][ni] = __builtin_amdgcn_mfma_f32_16x16x32_bf16(af[mi], bfg[ni], acc[mi][ni], 0, 0, 0);
    }
    __syncthreads();
  }

  const int cl = l & 15, rl0 = (l >> 4) * 4;

  if constexpr ((FLAGS & GF_F32OUT) != 0) {
    constexpr int CST = BN + 4;
    float* Cs = (float*)smem;
    constexpr int NCH = BM / 64;
#pragma unroll
    for (int c = 0; c < NCH; ++c) {
      __syncthreads();
      if ((wr * (BM / 2)) / 64 == c) {
#pragma unroll
        for (int mi = 0; mi < MR; ++mi)
#pragma unroll
          for (int ni = 0; ni < NR; ++ni)
#pragma unroll
            for (int j = 0; j < 4; ++j) {
              const int rl = wr * (BM / 2) + mi * 16 + rl0 + j - c * 64;
              const int cc = wc * (BN / 2) + ni * 16 + cl;
              const int gn = n0 + cc;
              float v = acc[mi][ni][j];
              if ((FLAGS & GF_BIAS) && gn < N) v += bias[gn];
              Cs[rl * CST + cc] = v;
            }
      }
      __syncthreads();
      const int rr = t >> 2, qq = t & 3;
      const size_t gmr = (size_t)(m0 + c * 64 + rr);
#pragma unroll
      for (int i = 0; i < BN / 16; ++i) {
        const int col = qq * (BN / 4) + i * 4;
        const int gn = n0 + col;
        if (gn + 3 < N) {
          *(float4*)&((float*)Cout)[gmr * ldc + gn] = *(const float4*)&Cs[rr * CST + col];
        } else {
#pragma unroll
          for (int c2 = 0; c2 < 4; ++c2)
            if (gn + c2 < N) ((float*)Cout)[gmr * ldc + gn + c2] = Cs[rr * CST + col + c2];
        }
      }
    }
  } else {
    constexpr int CST = BN + 8;
    unsigned short* Cs = (unsigned short*)smem;
    float lsum = 0.f, lsq = 0.f;
#pragma unroll
    for (int mi = 0; mi < MR; ++mi)
#pragma unroll
      for (int ni = 0; ni < NR; ++ni)
#pragma unroll
        for (int j = 0; j < 4; ++j) {
          const int rl = wr * (BM / 2) + mi * 16 + rl0 + j;
          const int cc = wc * (BN / 2) + ni * 16 + cl;
          const int gm = m0 + rl, gn = n0 + cc;
          float v = acc[mi][ni][j];
          if ((FLAGS & GF_BIAS) && gn < N) v += bias[gn];
          if (FLAGS & GF_RESID) v += b2f(Rz[(size_t)gm * ldc + gn]);
          if ((FLAGS & GF_POSENC) && gn < N) {
            const int srow = gm & (SS - 1);
            float freq = expf(-(2.0f * gn / 224.0f) * 9.210340371976184f);
            float ang = (float)srow * freq;
            v += (gn & 1) ? cosf(ang) : sinf(ang);
          }
          if (FLAGS & GF_RELU) v = fmaxf(v, 0.f);
          if ((FLAGS & GF_STAT) && gn < N) { lsum += v; lsq += v * v; }
          Cs[rl * CST + cc] = f2b(v);
        }
    __syncthreads();
#pragma unroll
    for (int it = 0; it < BM / 32; ++it) {
      const int rr = it * 32 + (t >> 3), qq = t & 7;
      const size_t gm = (size_t)(m0 + rr);
      *(uint4*)&((unsigned short*)Cout)[gm * ldc + n0 + qq * 8] =
          *(const uint4*)&Cs[rr * CST + qq * 8];
    }
    if constexpr ((FLAGS & GF_STAT) != 0) {
#pragma unroll
      for (int o2 = 32; o2 > 0; o2 >>= 1) {
        lsum += __shfl_down(lsum, o2); lsq += __shfl_down(lsq, o2);
      }
      if (l == 0) { red[w * 2] = lsum; red[w * 2 + 1] = lsq; }
      __syncthreads();
      if (t == 0) {
        float* so = statOut + ((m0 >> 10) << 1);
        atomicAdd(&so[0], red[0] + red[2] + red[4] + red[6]);
        atomicAdd(&so[1], red[1] + red[3] + red[5] + red[7]);
      }
    }
  }
}

__global__ void zero_stats(float* __restrict__ st)
{
  if (threadIdx.x < 128) st[threadIdx.x] = 0.f;
}

// ---------------------------------------------------------------------------
// Weight prep via LDS 32x32 transpose: fp32 [K][N] -> bf16 [Np][Kp] padded.
// ---------------------------------------------------------------------------
__global__ __launch_bounds__(256) void prep_wt2(
    const float* __restrict__ W, unsigned short* __restrict__ O,
    int K, int N, int Kp, int Np, size_t sW, size_t sO)
{
  const int ll = blockIdx.y;
  const int tx = Np >> 5;
  const int tn = blockIdx.x % tx, tk = blockIdx.x / tx;
  const int n0 = tn * 32, k0 = tk * 32;
  const float* Wl = W + sW * ll;
  unsigned short* Ol = O + sO * ll;
  __shared__ float T[32][36];
  {
    const int r = threadIdx.x >> 3, c4 = (threadIdx.x & 7) * 4;
    const int k = k0 + r, n = n0 + c4;
    float4 v = make_float4(0.f, 0.f, 0.f, 0.f);
    if (k < K) {
      if (n + 3 < N) v = *(const float4*)&Wl[(size_t)k * N + n];
      else {
        if (n + 0 < N) v.x = Wl[(size_t)k * N + n + 0];
        if (n + 1 < N) v.y = Wl[(size_t)k * N + n + 1];
        if (n + 2 < N) v.z = Wl[(size_t)k * N + n + 2];
        if (n + 3 < N) v.w = Wl[(size_t)k * N + n + 3];
      }
    }
    *(float4*)&T[r][c4] = v;
  }
  __syncthreads();
  {
    const int nl = threadIdx.x >> 3, k4 = (threadIdx.x & 7) * 4;
    ushort4 u;
    u.x = f2b(T[k4 + 0][nl]); u.y = f2b(T[k4 + 1][nl]);
    u.z = f2b(T[k4 + 2][nl]); u.w = f2b(T[k4 + 3][nl]);
    *(ushort4*)&Ol[(size_t)(n0 + nl) * Kp + k0 + k4] = u;
  }
}

__global__ void prep_wqkv(const float* __restrict__ Wq, const float* __restrict__ Wk,
                          const float* __restrict__ Wv, const float* __restrict__ bq,
                          const float* __restrict__ bk, const float* __restrict__ bv,
                          unsigned short* __restrict__ O, float* __restrict__ bcat)
{
  const int ll = blockIdx.y;
  const int id = blockIdx.x * 256 + threadIdx.x;   // < 704*256
  const int k = id & 255;
  const int n = id >> 8;
  float v = 0.f;
  if (n < 672 && k < 224) {
    const int which = n / 224, colin = n % 224;
    const int h = colin / 28, kk = colin % 28;
    const float* src = which == 0 ? Wq : (which == 1 ? Wk : Wv);
    v = src[(((size_t)ll * 8 + h) * 224 + k) * 28 + kk];
  }
  O[(size_t)ll * (704 * 256) + (size_t)n * 256 + k] = f2b(v);
  if (id < 672) {
    const int which = id / 224, colin = id % 224;
    const int h = colin / 28, kk = colin % 28;
    const float* src = which == 0 ? bq : (which == 1 ? bk : bv);
    bcat[ll * 672 + id] = src[((size_t)ll * 8 + h) * 28 + kk];
  }
}

__global__ void prep_x(const float* __restrict__ x, unsigned short* __restrict__ xb)
{
  const size_t i = ((size_t)blockIdx.x * 256 + threadIdx.x) * 4;
  float4 v = *(const float4*)(x + i);
  ushort4 o;
  o.x = f2b(v.x); o.y = f2b(v.y); o.z = f2b(v.z); o.w = f2b(v.w);
  *(ushort4*)(xb + i) = o;
}

// ---------------------------------------------------------------------------
// Flash attention, fp32 math on bf16 tensors. Grid: (B*H, S/32), heavy first.
// 8 threads per q-row split the KV stream; combined via shfl_xor.
// ---------------------------------------------------------------------------
__global__ __launch_bounds__(256) void attn_flash(const unsigned short* __restrict__ qkv,
                                                  unsigned short* __restrict__ o)
{
  const int bh = blockIdx.x;
  const int qt = (int)gridDim.y - 1 - (int)blockIdx.y;   // heavy blocks first
  const int b = bh >> 3, h = bh & 7;
  const int tid = threadIdx.x;
  const int qr = tid >> 3, sl = tid & 7;
  const int qrow = qt * 32 + qr;
  const float scale = 0.1889822365046136f;  // 1/sqrt(28)

  __shared__ float Ks[64][28];
  __shared__ float Vs[64][28];

  float qv[28], acc[28];
  {
    const unsigned short* qp = qkv + ((size_t)(b * SS + qrow)) * 704 + h * 28;
#pragma unroll
    for (int c4 = 0; c4 < 7; ++c4) {
      ushort4 u = *(const ushort4*)(qp + c4 * 4);
      qv[c4 * 4 + 0] = b2f(u.x) * scale;
      qv[c4 * 4 + 1] = b2f(u.y) * scale;
      qv[c4 * 4 + 2] = b2f(u.z) * scale;
      qv[c4 * 4 + 3] = b2f(u.w) * scale;
    }
#pragma unroll
    for (int j = 0; j < 28; ++j) acc[j] = 0.f;
  }
  float m = -INFINITY, l = 0.f;

  const int ntiles = (qt + 2) >> 1;
  for (int tile = 0; tile < ntiles; ++tile) {
    const int t0 = tile * 64;
    __syncthreads();
    for (int idx = tid; idx < 448; idx += 256) {
      const int r = idx / 7, c4 = idx % 7;
      const unsigned short* kp = qkv + ((size_t)(b * SS + t0 + r)) * 704 + 224 + h * 28 + c4 * 4;
      ushort4 ku = *(const ushort4*)kp;
      ushort4 vu = *(const ushort4*)(kp + 224);
      *(float4*)&Ks[r][c4 * 4] = make_float4(b2f(ku.x), b2f(ku.y), b2f(ku.z), b2f(ku.w));
      *(float4*)&Vs[r][c4 * 4] = make_float4(b2f(vu.x), b2f(vu.y), b2f(vu.z), b2f(vu.w));
    }
    __syncthreads();

    float sc[8];
    float tmax = -INFINITY;
    const bool masked = (tile == ntiles - 1);
#pragma unroll
    for (int i = 0; i < 8; ++i) {
      const int r = sl + i * 8;
      float d0 = 0.f;
#pragma unroll
      for (int j4 = 0; j4 < 7; ++j4) {
        float4 k4 = *(const float4*)&Ks[r][j4 * 4];
        d0 = fmaf(qv[j4 * 4 + 0], k4.x, d0);
        d0 = fmaf(qv[j4 * 4 + 1], k4.y, d0);
        d0 = fmaf(qv[j4 * 4 + 2], k4.z, d0);
        d0 = fmaf(qv[j4 * 4 + 3], k4.w, d0);
      }
      sc[i] = (masked && (t0 + r > qrow)) ? -INFINITY : d0;
      tmax = fmaxf(tmax, sc[i]);
    }
    if (tmax > m) {
      const float r2 = __expf(m - tmax);  // m=-inf first time -> 0
      l *= r2;
#pragma unroll
      for (int j = 0; j < 28; ++j) acc[j] *= r2;
      m = tmax;
    }
    if (m > -INFINITY) {
#pragma unroll
      for (int i = 0; i < 8; ++i) {
        const float p = __expf(sc[i] - m);  // masked: exp(-inf)=0
        l += p;
        const int r = sl + i * 8;
#pragma unroll
        for (int j4 = 0; j4 < 7; ++j4) {
          float4 v4 = *(const float4*)&Vs[r][j4 * 4];
          acc[j4 * 4 + 0] = fmaf(p, v4.x, acc[j4 * 4 + 0]);
          acc[j4 * 4 + 1] = fmaf(p, v4.y, acc[j4 * 4 + 1]);
          acc[j4 * 4 + 2] = fmaf(p, v4.z, acc[j4 * 4 + 2]);
          acc[j4 * 4 + 3] = fmaf(p, v4.w, acc[j4 * 4 + 3]);
        }
      }
    }
  }

  // combine the 8 slices within the octet
  const float msave = m;
#pragma unroll
  for (int d = 1; d < 8; d <<= 1) m = fmaxf(m, __shfl_xor(m, d));
  const float cs = __expf(msave - m);   // slice never contributed -> 0
  l *= cs;
#pragma unroll
  for (int d = 1; d < 8; d <<= 1) l += __shfl_xor(l, d);
  const float inv = 1.0f / l;
#pragma unroll
  for (int j = 0; j < 28; ++j) {
    float a = acc[j] * cs;
#pragma unroll
    for (int d = 1; d < 8; d <<= 1) a += __shfl_xor(a, d);
    acc[j] = a * inv;
  }
  if (sl < 7) {
    unsigned short* op = o + ((size_t)(b * SS + qrow)) * 256 + h * 28;
    ushort4 u;
    u.x = f2b(acc[sl * 4 + 0]); u.y = f2b(acc[sl * 4 + 1]);
    u.z = f2b(acc[sl * 4 + 2]); u.w = f2b(acc[sl * 4 + 3]);
    *(ushort4*)(op + sl * 4) = u;
  }
}

// ---------------------------------------------------------------------------
// LayerNorm over (S,D) per batch, bf16 tensors (stride 256, 224 real cols).
// Stats come pre-reduced (2 floats per batch) from GEMM-epilogue atomics.
// ---------------------------------------------------------------------------
__global__ __launch_bounds__(256) void ln_apply(
    const unsigned short* __restrict__ x, const float* __restrict__ w,
    const float* __restrict__ bb, const float* __restrict__ st,
    unsigned short* __restrict__ y)
{
  const int b = blockIdx.x / 112;
  const float s1 = st[b * 2], s2 = st[b * 2 + 1];
  const float mu = s1 / (float)SD;
  const float rstd = rsqrtf(s2 / (float)SD - mu * mu + 1e-5f);
  const int chunk = blockIdx.x * 256 + threadIdx.x;
  const int r = chunk / 28, cc = chunk % 28;
  const int s = r & 1023;
  uint4 u = *(const uint4*)(x + (size_t)r * 256 + cc * 8);
  const float* wp = w + (size_t)s * 224 + cc * 8;
  const float* bp = bb + (size_t)s * 224 + cc * 8;
  float4 w0 = *(const float4*)wp, w1 = *(const float4*)(wp + 4);
  float4 b0 = *(const float4*)bp, b1 = *(const float4*)(bp + 4);
  float wv[8] = {w0.x, w0.y, w0.z, w0.w, w1.x, w1.y, w1.z, w1.w};
  float bv[8] = {b0.x, b0.y, b0.z, b0.w, b1.x, b1.y, b1.z, b1.w};
  const unsigned* up = (const unsigned*)&u;
  uint4 ov;
  unsigned* op = (unsigned*)&ov;
#pragma unroll
  for (int q = 0; q < 4; ++q) {
    float f0 = bits2f(up[q] << 16), f1 = bits2f(up[q] & 0xFFFF0000u);
    float y0 = (f0 - mu) * rstd * wv[q * 2] + bv[q * 2];
    float y1 = (f1 - mu) * rstd * wv[q * 2 + 1] + bv[q * 2 + 1];
    op[q] = (unsigned)f2b(y0) | ((unsigned)f2b(y1) << 16);
  }
  *(uint4*)(y + (size_t)r * 256 + cc * 8) = ov;
}

__global__ __launch_bounds__(256) void ln_part2(
    const unsigned short* __restrict__ x, const float* __restrict__ w,
    const float* __restrict__ bb, const float* __restrict__ stA,
    float* __restrict__ part2)
{
  const int b = blockIdx.y, g = blockIdx.x;
  const float s1 = stA[b * 2], s2 = stA[b * 2 + 1];
  const float mu = s1 / (float)SD;
  const float rstd = rsqrtf(s2 / (float)SD - mu * mu + 1e-5f);
  const unsigned short* base = x + ((size_t)b * 1024 + g * 16) * 256;
  float sum = 0.f, sq = 0.f;
  for (int c = threadIdx.x; c < 448; c += 256) {
    const int r = c / 28, cc = c % 28;
    const int s = g * 16 + r;
    uint4 u = *(const uint4*)(base + (size_t)r * 256 + cc * 8);
    const float* wp = w + (size_t)s * 224 + cc * 8;
    const float* bp = bb + (size_t)s * 224 + cc * 8;
    float4 w0 = *(const float4*)wp, w1 = *(const float4*)(wp + 4);
    float4 b0 = *(const float4*)bp, b1 = *(const float4*)(bp + 4);
    float wv[8] = {w0.x, w0.y, w0.z, w0.w, w1.x, w1.y, w1.z, w1.w};
    float bv[8] = {b0.x, b0.y, b0.z, b0.w, b1.x, b1.y, b1.z, b1.w};
    const unsigned* up = (const unsigned*)&u;
#pragma unroll
    for (int q = 0; q < 4; ++q) {
      float f0 = bits2f(up[q] << 16), f1 = bits2f(up[q] & 0xFFFF0000u);
      float y0 = (f0 - mu) * rstd * wv[q * 2] + bv[q * 2];
      float y1 = (f1 - mu) * rstd * wv[q * 2 + 1] + bv[q * 2 + 1];
      sum += y0 + y1; sq += y0 * y0 + y1 * y1;
    }
  }
  __shared__ float sA[4], sB[4];
#pragma unroll
  for (int o2 = 32; o2 > 0; o2 >>= 1) { sum += __shfl_down(sum, o2); sq += __shfl_down(sq, o2); }
  if ((threadIdx.x & 63) == 0) { sA[threadIdx.x >> 6] = sum; sB[threadIdx.x >> 6] = sq; }
  __syncthreads();
  if (threadIdx.x == 0) {
    part2[((size_t)b * 64 + g) * 2] = sA[0] + sA[1] + sA[2] + sA[3];
    part2[((size_t)b * 64 + g) * 2 + 1] = sB[0] + sB[1] + sB[2] + sB[3];
  }
}

__global__ __launch_bounds__(256) void ln_apply2(
    const unsigned short* __restrict__ x, const float* __restrict__ w,
    const float* __restrict__ bb, const float* __restrict__ stA,
    const float* __restrict__ part2, unsigned short* __restrict__ y)
{
  __shared__ float sh[2];
  const int tid = threadIdx.x;
  const int b = blockIdx.x / 112;
  const float s1 = stA[b * 2], s2 = stA[b * 2 + 1];
  const float mu1 = s1 / (float)SD;
  const float rs1 = rsqrtf(s2 / (float)SD - mu1 * mu1 + 1e-5f);
  if (tid < 64) {
    float p1 = part2[((size_t)b * 64 + tid) * 2];
    float p2 = part2[((size_t)b * 64 + tid) * 2 + 1];
#pragma unroll
    for (int o2 = 32; o2 > 0; o2 >>= 1) { p1 += __shfl_down(p1, o2); p2 += __shfl_down(p2, o2); }
    if (tid == 0) {
      float m2 = p1 / (float)SD;
      sh[0] = m2; sh[1] = rsqrtf(p2 / (float)SD - m2 * m2 + 1e-5f);
    }
  }
  __syncthreads();
  const float mu2 = sh[0], rs2 = sh[1];
  const int chunk = blockIdx.x * 256 + tid;
  const int r = chunk / 28, cc = chunk % 28;
  const int s = r & 1023;
  uint4 u = *(const uint4*)(x + (size_t)r * 256 + cc * 8);
  const float* wp = w + (size_t)s * 224 + cc * 8;
  const float* bp = bb + (size_t)s * 224 + cc * 8;
  float4 w0 = *(const float4*)wp, w1 = *(const float4*)(wp + 4);
  float4 b0 = *(const float4*)bp, b1 = *(const float4*)(bp + 4);
  float wv[8] = {w0.x, w0.y, w0.z, w0.w, w1.x, w1.y, w1.z, w1.w};
  float bv[8] = {b0.x, b0.y, b0.z, b0.w, b1.x, b1.y, b1.z, b1.w};
  const unsigned* up = (const unsigned*)&u;
  uint4 ov;
  unsigned* op = (unsigned*)&ov;
#pragma unroll
  for (int q = 0; q < 4; ++q) {
    float f0 = bits2f(up[q] << 16), f1 = bits2f(up[q] & 0xFFFF0000u);
    float y0 = (f0 - mu1) * rs1 * wv[q * 2] + bv[q * 2];
    float y1 = (f1 - mu1) * rs1 * wv[q * 2 + 1] + bv[q * 2 + 1];
    float z0 = (y0 - mu2) * rs2 * wv[q * 2] + bv[q * 2];
    float z1 = (y1 - mu2) * rs2 * wv[q * 2 + 1] + bv[q * 2 + 1];
    op[q] = (unsigned)f2b(z0) | ((unsigned)f2b(z1) << 16);
  }
  *(uint4*)(y + (size_t)r * 256 + cc * 8) = ov;
}

// ---------------------------------------------------------------------------
// Row softmax over V=8000, in place on d_out (fp32).
// ---------------------------------------------------------------------------
__global__ __launch_bounds__(256) void softmax_rows(float* __restrict__ logits)
{
  const int row = blockIdx.x;
  float* p = logits + (size_t)row * VV;
  __shared__ float buf[VV];
  __shared__ float red[4];
  const int tid = threadIdx.x;

  float mx = -INFINITY;
  for (int i = tid; i < VV; i += 256) { float v = p[i]; buf[i] = v; mx = fmaxf(mx, v); }
#pragma unroll
  for (int o2 = 32; o2 > 0; o2 >>= 1) mx = fmaxf(mx, __shfl_down(mx, o2));
  if ((tid & 63) == 0) red[tid >> 6] = mx;
  __syncthreads();
  mx = fmaxf(fmaxf(red[0], red[1]), fmaxf(red[2], red[3]));
  __syncthreads();

  float s = 0.f;
  for (int i = tid; i < VV; i += 256) { float e = __expf(buf[i] - mx); buf[i] = e; s += e; }
#pragma unroll
  for (int o2 = 32; o2 > 0; o2 >>= 1) s += __shfl_down(s, o2);
  if ((tid & 63) == 0) red[tid >> 6] = s;
  __syncthreads();
  s = red[0] + red[1] + red[2] + red[3];
  const float inv = 1.0f / s;
  for (int i = tid; i < VV; i += 256) p[i] = buf[i] * inv;
}

// ---------------------------------------------------------------------------
extern "C" void kernel_launch(void* const* d_in, const int* in_sizes, int n_in,
                              void* d_out, int out_size, void* d_ws, size_t ws_size,
                              hipStream_t stream) {
  const float* x   = (const float*)d_in[0];
  const float* Wp  = (const float*)d_in[1];
  const float* bp  = (const float*)d_in[2];
  const float* Wq  = (const float*)d_in[3];
  const float* bq  = (const float*)d_in[4];
  const float* Wk  = (const float*)d_in[5];
  const float* bk  = (const float*)d_in[6];
  const float* Wv  = (const float*)d_in[7];
  const float* bv  = (const float*)d_in[8];
  const float* Wo  = (const float*)d_in[9];
  const float* bo  = (const float*)d_in[10];
  const float* W1  = (const float*)d_in[11];
  const float* b1  = (const float*)d_in[12];
  const float* W2  = (const float*)d_in[13];
  const float* b2  = (const float*)d_in[14];
  const float* W3  = (const float*)d_in[15];
  const float* b3  = (const float*)d_in[16];
  const float* lnw = (const float*)d_in[17];
  const float* lnb = (const float*)d_in[18];
  const float* Wf  = (const float*)d_in[19];
  const float* bf  = (const float*)d_in[20];

  unsigned short* wsb = (unsigned short*)d_ws;
  unsigned short* wpT   = wsb + WP;
  unsigned short* wqkvT = wsb + WQKV;
  unsigned short* woT   = wsb + WO;
  unsigned short* w1T   = wsb + W1T;
  unsigned short* w2T   = wsb + W2T;
  unsigned short* w3T   = wsb + W3T;
  unsigned short* wfT   = wsb + WFT;
  unsigned short* h     = wsb + HB;
  unsigned short* h2    = wsb + H2B;
  unsigned short* obuf  = wsb + OBUF;
  unsigned short* xb    = wsb + BIG;
  unsigned short* qkvb  = wsb + BIG;
  unsigned short* f1    = wsb + BIG;
  unsigned short* f2    = wsb + BIG + (size_t)4096 * 640;
  float* bcat  = (float*)((char*)d_ws + FBYTE);
  float* part2 = bcat + LLl * 672;
  float* stats = part2 + 512;     // 128 floats: 8 layers x 2 slots x (4 batches x 2)

  // ---- prep ----
  zero_stats<<<1, 128, 0, stream>>>(stats);
  prep_x<<<3072, 256, 0, stream>>>(x, xb);
  prep_wt2<<<dim3(192, 1), 256, 0, stream>>>(Wp, wpT, 768, 224, 768, 256, 0, 0);
  prep_wqkv<<<dim3(704, 8), 256, 0, stream>>>(Wq, Wk, Wv, bq, bk, bv, wqkvT, bcat);
  prep_wt2<<<dim3(64, 8), 256, 0, stream>>>(Wo, woT, 224, 224, 256, 256,
                                            (size_t)224 * 224, (size_t)256 * 256);
  prep_wt2<<<dim3(160, 8), 256, 0, stream>>>(W1, w1T, 224, 600, 256, 640,
                                             (size_t)224 * 600, (size_t)640 * 256);
  prep_wt2<<<dim3(400, 8), 256, 0, stream>>>(W2, w2T, 600, 600, 640, 640,
                                             (size_t)600 * 600, (size_t)640 * 640);
  prep_wt2<<<dim3(160, 8), 256, 0, stream>>>(W3, w3T, 600, 224, 640, 256,
                                             (size_t)600 * 224, (size_t)256 * 640);
  prep_wt2<<<dim3(2016, 1), 256, 0, stream>>>(Wf, wfT, 224, 8000, 256, 8064, 0, 0);

  // ---- proj + posenc: h = x @ Wp + bp + pe ----
  gemm_mfma<64, 64, GF_BIAS | GF_POSENC><<<dim3(4, 64), 256, 0, stream>>>(
      xb, wpT, bp, nullptr, h, 768, 224, 256, nullptr);

  for (int l = 0; l < LLl; ++l) {
    float* stA = stats + (size_t)(l * 2) * 8;
    float* stB = stats + (size_t)(l * 2 + 1) * 8;
    gemm_mfma<64, 64, GF_BIAS><<<dim3(11, 64), 256, 0, stream>>>(
        h, wqkvT + (size_t)l * 704 * 256, bcat + l * 672, nullptr, qkvb, 256, 672, 704, nullptr);
    attn_flash<<<dim3(BB * 8, SS / 32), 256, 0, stream>>>(qkvb, obuf);
    gemm_mfma<64, 64, GF_BIAS | GF_RESID | GF_STAT><<<dim3(4, 64), 256, 0, stream>>>(
        obuf, woT + (size_t)l * 256 * 256, bo + (size_t)l * 224, h, h2, 256, 224, 256, stA);
    ln_apply<<<448, 256, 0, stream>>>(h2, lnw + (size_t)l * SD, lnb + (size_t)l * SD, stA, h);
    gemm_mfma<64, 64, GF_BIAS | GF_RELU><<<dim3(10, 64), 256, 0, stream>>>(
        h, w1T + (size_t)l * 640 * 256, b1 + (size_t)l * 600, nullptr, f1, 256, 600, 640, nullptr);
    gemm_mfma<64, 64, GF_BIAS | GF_RELU><<<dim3(10, 64), 256, 0, stream>>>(
        f1, w2T + (size_t)l * 640 * 640, b2 + (size_t)l * 600, nullptr, f2, 640, 600, 640, nullptr);
    gemm_mfma<64, 64, GF_BIAS | GF_RESID | GF_STAT><<<dim3(4, 64), 256, 0, stream>>>(
        f2, w3T + (size_t)l * 256 * 640, b3 + (size_t)l * 224, h, h2, 640, 224, 256, stB);
    ln_part2<<<dim3(64, BB), 256, 0, stream>>>(h2, lnw + (size_t)l * SD, lnb + (size_t)l * SD,
                                               stB, part2);
    ln_apply2<<<448, 256, 0, stream>>>(h2, lnw + (size_t)l * SD, lnb + (size_t)l * SD,
                                       stB, part2, h);
  }

  // ---- logits (fp32 out, m-fastest block order) + softmax ----
  gemm_mfma<128, 128, GF_BIAS | GF_F32OUT | GF_SWAP><<<dim3(32, 63), 256, 0, stream>>>(
      h, wfT, bf, nullptr, (float*)d_out, 256, 8000, 8000, nullptr);
  softmax_rows<<<4096, 256, 0, stream>>>((float*)d_out);
}

// Round 5
// 1637.951 us; speedup vs baseline: 4.9832x; 1.0139x over previous
//
#include <hip/hip_runtime.h>
#include <math.h>

#define GF_BIAS   1
#define GF_RELU   2
#define GF_RESID  4
#define GF_POSENC 8
#define GF_F32OUT 16
#define GF_STAT   32
#define GF_SWAP   64

namespace {
constexpr int BB = 4, SS = 1024, DD = 224, FFF = 600, VV = 8000, LLl = 8;
constexpr int SD = SS * DD;  // 229376

// workspace layout, bf16 element offsets
constexpr size_t WP   = 0;                         // [256][768]
constexpr size_t WQKV = WP + (size_t)256 * 768;    // L x [704][256]
constexpr size_t WO   = WQKV + (size_t)LLl * 704 * 256;
constexpr size_t W1T  = WO + (size_t)LLl * 256 * 256;
constexpr size_t W2T  = W1T + (size_t)LLl * 640 * 256;
constexpr size_t W3T  = W2T + (size_t)LLl * 640 * 640;
constexpr size_t WFT  = W3T + (size_t)LLl * 256 * 640;   // [8064][256]
constexpr size_t HB   = WFT + (size_t)8064 * 256;
constexpr size_t H2B  = HB + (size_t)4096 * 256;
constexpr size_t OBUF = H2B + (size_t)4096 * 256;
constexpr size_t BIG  = OBUF + (size_t)4096 * 256;       // xb | qkv | f1,f2
constexpr size_t ENDB = BIG + (size_t)2 * 4096 * 640;
constexpr size_t FBYTE = ENDB * 2;                       // float region byte offset
}

using short8 = __attribute__((ext_vector_type(8))) short;
using f32x4  = __attribute__((ext_vector_type(4))) float;

__device__ __forceinline__ float bits2f(unsigned u) {
  union { unsigned u; float f; } v; v.u = u; return v.f;
}
__device__ __forceinline__ unsigned short f2b(float f) {
  union { float f; unsigned u; } v; v.f = f;
  unsigned r = v.u + 0x7FFFu + ((v.u >> 16) & 1u);
  return (unsigned short)(r >> 16);
}
__device__ __forceinline__ float b2f(unsigned short b) {
  return bits2f((unsigned)b << 16);
}

// ---------------------------------------------------------------------------
// bf16 MFMA GEMM: C[M,Npad] = A[M,Kp] @ Bt[Npad,Kp]^T, epilogue fused.
// 256 thr = 4 waves (2x2), 16x16x32 fragments. LDS tiles [R][64] bf16,
// XOR-swizzled, reg double-buffer. C written via LDS stage -> coalesced rows.
// ---------------------------------------------------------------------------
template <int BM, int BN, int FLAGS>
__global__ __launch_bounds__(256) void gemm_mfma(
    const unsigned short* __restrict__ A, const unsigned short* __restrict__ Bt,
    const float* __restrict__ bias, const unsigned short* __restrict__ Rz,
    void* __restrict__ Cout, int Kp, int N, int ldc, float* __restrict__ statOut)
{
  constexpr int MR = BM / 32, NR = BN / 32;
  constexpr int APT = BM / 32, BPT = BN / 32;
  constexpr int ABY = BM * 128, BBY = BN * 128;   // bytes
  constexpr int CBY = (FLAGS & GF_F32OUT) ? (64 * (BN + 4) * 4) : (BM * (BN + 8) * 2);
  constexpr int SBY = (ABY + BBY) > CBY ? (ABY + BBY) : CBY;
  __shared__ __align__(16) char smem[SBY];
  __shared__ float red[8];
  unsigned short* sA = (unsigned short*)smem;
  unsigned short* sB = (unsigned short*)(smem + ABY);
  const int t = threadIdx.x;
  const int l = t & 63;
  const int w = t >> 6, wr = w >> 1, wc = w & 1;
  const int m0 = ((FLAGS & GF_SWAP) ? blockIdx.x : blockIdx.y) * BM;
  const int n0 = ((FLAGS & GF_SWAP) ? blockIdx.y : blockIdx.x) * BN;
  const int nk = Kp >> 6;

  int aoff[APT], ar[APT], ac[APT];
#pragma unroll
  for (int p = 0; p < APT; ++p) {
    int off = (t + p * 256) * 16;
    int r = off >> 7;
    int cb = (off & 127) ^ ((r & 7) << 4);
    aoff[p] = off; ar[p] = r; ac[p] = cb >> 1;
  }
  int boff[BPT], br[BPT], bc[BPT];
#pragma unroll
  for (int p = 0; p < BPT; ++p) {
    int off = (t + p * 256) * 16;
    int r = off >> 7;
    int cb = (off & 127) ^ ((r & 7) << 4);
    boff[p] = off; br[p] = r; bc[p] = cb >> 1;
  }

  const unsigned short* Ab = A + (size_t)m0 * Kp;
  const unsigned short* Bb = Bt + (size_t)n0 * Kp;

  uint4 ra[APT], rb[BPT];
#pragma unroll
  for (int p = 0; p < APT; ++p) ra[p] = *(const uint4*)(Ab + (size_t)ar[p] * Kp + ac[p]);
#pragma unroll
  for (int p = 0; p < BPT; ++p) rb[p] = *(const uint4*)(Bb + (size_t)br[p] * Kp + bc[p]);

  f32x4 acc[MR][NR];
#pragma unroll
  for (int i = 0; i < MR; ++i)
#pragma unroll
    for (int j = 0; j < NR; ++j) acc[i][j] = {0.f, 0.f, 0.f, 0.f};

  for (int kt = 0; kt < nk; ++kt) {
#pragma unroll
    for (int p = 0; p < APT; ++p) *(uint4*)((char*)sA + aoff[p]) = ra[p];
#pragma unroll
    for (int p = 0; p < BPT; ++p) *(uint4*)((char*)sB + boff[p]) = rb[p];
    __syncthreads();
    if (kt + 1 < nk) {
      const int k1 = (kt + 1) * 64;
#pragma unroll
      for (int p = 0; p < APT; ++p) ra[p] = *(const uint4*)(Ab + (size_t)ar[p] * Kp + k1 + ac[p]);
#pragma unroll
      for (int p = 0; p < BPT; ++p) rb[p] = *(const uint4*)(Bb + (size_t)br[p] * Kp + k1 + bc[p]);
    }
#pragma unroll
    for (int kh = 0; kh < 2; ++kh) {
      short8 af[MR], bfg[NR];
#pragma unroll
      for (int mi = 0; mi < MR; ++mi) {
        const int row = wr * (BM / 2) + mi * 16 + (l & 15);
        const int byte = (row * 128 + kh * 64 + (l >> 4) * 16) ^ ((row & 7) << 4);
        af[mi] = *(const short8*)((const char*)sA + byte);
      }
#pragma unroll
      for (int ni = 0; ni < NR; ++ni) {
        const int row = wc * (BN / 2) + ni * 16 + (l & 15);
        const int byte = (row * 128 + kh * 64 + (l >> 4) * 16) ^ ((row & 7) << 4);
        bfg[ni] = *(const short8*)((const char*)sB + byte);
      }
#pragma unroll
      for (int mi = 0; mi < MR; ++mi)
#pragma unroll
        for (int ni = 0; ni < NR; ++ni)
          acc[mi][ni] = __builtin_amdgcn_mfma_f32_16x16x32_bf16(af[mi], bfg[ni], acc[mi][ni], 0, 0, 0);
    }
    __syncthreads();
  }

  const int cl = l & 15, rl0 = (l >> 4) * 4;

  if constexpr ((FLAGS & GF_F32OUT) != 0) {
    constexpr int CST = BN + 4;
    float* Cs = (float*)smem;
    constexpr int NCH = BM / 64;
#pragma unroll
    for (int c = 0; c < NCH; ++c) {
      __syncthreads();
      if ((wr * (BM / 2)) / 64 == c) {
#pragma unroll
        for (int mi = 0; mi < MR; ++mi)
#pragma unroll
          for (int ni = 0; ni < NR; ++ni)
#pragma unroll
            for (int j = 0; j < 4; ++j) {
              const int rl = wr * (BM / 2) + mi * 16 + rl0 + j - c * 64;
              const int cc = wc * (BN / 2) + ni * 16 + cl;
              const int gn = n0 + cc;
              float v = acc[mi][ni][j];
              if ((FLAGS & GF_BIAS) && gn < N) v += bias[gn];
              Cs[rl * CST + cc] = v;
            }
      }
      __syncthreads();
      // conflict-free contiguous-chunk readout (64 consecutive 16B chunks/wave)
      constexpr int CPR = BN / 4;          // 16B chunks per row
      constexpr int NIT = (64 * CPR) / 256;
#pragma unroll
      for (int i = 0; i < NIT; ++i) {
        const int ch = i * 256 + t;
        const int rr = ch / CPR, c4 = ch % CPR;
        const int gn = n0 + c4 * 4;
        const size_t gmr = (size_t)(m0 + c * 64 + rr);
        if (gn + 3 < N) {
          *(float4*)&((float*)Cout)[gmr * ldc + gn] = *(const float4*)&Cs[rr * CST + c4 * 4];
        } else {
#pragma unroll
          for (int c2 = 0; c2 < 4; ++c2)
            if (gn + c2 < N) ((float*)Cout)[gmr * ldc + gn + c2] = Cs[rr * CST + c4 * 4 + c2];
        }
      }
    }
  } else {
    constexpr int CST = BN + 8;
    unsigned short* Cs = (unsigned short*)smem;
    float lsum = 0.f, lsq = 0.f;
#pragma unroll
    for (int mi = 0; mi < MR; ++mi)
#pragma unroll
      for (int ni = 0; ni < NR; ++ni)
#pragma unroll
        for (int j = 0; j < 4; ++j) {
          const int rl = wr * (BM / 2) + mi * 16 + rl0 + j;
          const int cc = wc * (BN / 2) + ni * 16 + cl;
          const int gm = m0 + rl, gn = n0 + cc;
          float v = acc[mi][ni][j];
          if ((FLAGS & GF_BIAS) && gn < N) v += bias[gn];
          if (FLAGS & GF_RESID) v += b2f(Rz[(size_t)gm * ldc + gn]);
          if ((FLAGS & GF_POSENC) && gn < N) {
            const int srow = gm & (SS - 1);
            float freq = expf(-(2.0f * gn / 224.0f) * 9.210340371976184f);
            float ang = (float)srow * freq;
            v += (gn & 1) ? cosf(ang) : sinf(ang);
          }
          if (FLAGS & GF_RELU) v = fmaxf(v, 0.f);
          if ((FLAGS & GF_STAT) && gn < N) { lsum += v; lsq += v * v; }
          Cs[rl * CST + cc] = f2b(v);
        }
    __syncthreads();
#pragma unroll
    for (int it = 0; it < BM / 32; ++it) {
      const int rr = it * 32 + (t >> 3), qq = t & 7;
      const size_t gm = (size_t)(m0 + rr);
      *(uint4*)&((unsigned short*)Cout)[gm * ldc + n0 + qq * 8] =
          *(const uint4*)&Cs[rr * CST + qq * 8];
    }
    if constexpr ((FLAGS & GF_STAT) != 0) {
#pragma unroll
      for (int o2 = 32; o2 > 0; o2 >>= 1) {
        lsum += __shfl_down(lsum, o2); lsq += __shfl_down(lsq, o2);
      }
      if (l == 0) { red[w * 2] = lsum; red[w * 2 + 1] = lsq; }
      __syncthreads();
      if (t == 0) {
        float* so = statOut + ((m0 >> 10) << 1);
        atomicAdd(&so[0], red[0] + red[2] + red[4] + red[6]);
        atomicAdd(&so[1], red[1] + red[3] + red[5] + red[7]);
      }
    }
  }
}

__global__ void zero_stats(float* __restrict__ st)
{
  if (threadIdx.x < 128) st[threadIdx.x] = 0.f;
}

// ---------------------------------------------------------------------------
// Weight prep via LDS 32x32 transpose: fp32 [K][N] -> bf16 [Np][Kp] padded.
// ---------------------------------------------------------------------------
__global__ __launch_bounds__(256) void prep_wt2(
    const float* __restrict__ W, unsigned short* __restrict__ O,
    int K, int N, int Kp, int Np, size_t sW, size_t sO)
{
  const int ll = blockIdx.y;
  const int tx = Np >> 5;
  const int tn = blockIdx.x % tx, tk = blockIdx.x / tx;
  const int n0 = tn * 32, k0 = tk * 32;
  const float* Wl = W + sW * ll;
  unsigned short* Ol = O + sO * ll;
  __shared__ float T[32][36];
  {
    const int r = threadIdx.x >> 3, c4 = (threadIdx.x & 7) * 4;
    const int k = k0 + r, n = n0 + c4;
    float4 v = make_float4(0.f, 0.f, 0.f, 0.f);
    if (k < K) {
      if (n + 3 < N) v = *(const float4*)&Wl[(size_t)k * N + n];
      else {
        if (n + 0 < N) v.x = Wl[(size_t)k * N + n + 0];
        if (n + 1 < N) v.y = Wl[(size_t)k * N + n + 1];
        if (n + 2 < N) v.z = Wl[(size_t)k * N + n + 2];
        if (n + 3 < N) v.w = Wl[(size_t)k * N + n + 3];
      }
    }
    *(float4*)&T[r][c4] = v;
  }
  __syncthreads();
  {
    const int nl = threadIdx.x >> 3, k4 = (threadIdx.x & 7) * 4;
    ushort4 u;
    u.x = f2b(T[k4 + 0][nl]); u.y = f2b(T[k4 + 1][nl]);
    u.z = f2b(T[k4 + 2][nl]); u.w = f2b(T[k4 + 3][nl]);
    *(ushort4*)&Ol[(size_t)(n0 + nl) * Kp + k0 + k4] = u;
  }
}

__global__ void prep_wqkv(const float* __restrict__ Wq, const float* __restrict__ Wk,
                          const float* __restrict__ Wv, const float* __restrict__ bq,
                          const float* __restrict__ bk, const float* __restrict__ bv,
                          unsigned short* __restrict__ O, float* __restrict__ bcat)
{
  const int ll = blockIdx.y;
  const int id = blockIdx.x * 256 + threadIdx.x;   // < 704*256
  const int k = id & 255;
  const int n = id >> 8;
  float v = 0.f;
  if (n < 672 && k < 224) {
    const int which = n / 224, colin = n % 224;
    const int h = colin / 28, kk = colin % 28;
    const float* src = which == 0 ? Wq : (which == 1 ? Wk : Wv);
    v = src[(((size_t)ll * 8 + h) * 224 + k) * 28 + kk];
  }
  O[(size_t)ll * (704 * 256) + (size_t)n * 256 + k] = f2b(v);
  if (id < 672) {
    const int which = id / 224, colin = id % 224;
    const int h = colin / 28, kk = colin % 28;
    const float* src = which == 0 ? bq : (which == 1 ? bk : bv);
    bcat[ll * 672 + id] = src[((size_t)ll * 8 + h) * 28 + kk];
  }
}

__global__ void prep_x(const float* __restrict__ x, unsigned short* __restrict__ xb)
{
  const size_t i = ((size_t)blockIdx.x * 256 + threadIdx.x) * 4;
  float4 v = *(const float4*)(x + i);
  ushort4 o;
  o.x = f2b(v.x); o.y = f2b(v.y); o.z = f2b(v.z); o.w = f2b(v.w);
  *(ushort4*)(xb + i) = o;
}

// ---------------------------------------------------------------------------
// MFMA flash attention. Grid: (B*H, S/64), heavy-first. 4 waves x 16 q-rows.
// KV tiles of 32; DK=28 padded to one K=32 MFMA step.
// Layouts (verified by the ref-checked GEMM): A row=l&15,k=(l>>4)*8+e;
// B col=l&15,k=(l>>4)*8+e; C col=l&15,row=(l>>4)*4+j.
// ---------------------------------------------------------------------------
__global__ __launch_bounds__(256) void attn_mfma(const unsigned short* __restrict__ qkv,
                                                 unsigned short* __restrict__ o)
{
  const int bh = blockIdx.x;
  const int qt = (int)gridDim.y - 1 - (int)blockIdx.y;   // heavy blocks first
  const int b = bh >> 3, h = bh & 7;
  const int tid = threadIdx.x;
  const int w = tid >> 6, l = tid & 63;
  const int cl = l & 15, g = l >> 4;
  const int qbase = qt * 64 + w * 16;
  const float scale = 0.1889822365046136f;  // 1/sqrt(28)

  __shared__ unsigned short Ks[32 * 40];
  __shared__ unsigned short Vt[32 * 40];
  __shared__ unsigned short Ps[4][16 * 40];

  // Q A-fragment: q-row = qbase+cl, d = g*8+e (d>=28 zero)
  short8 aq;
  {
    const unsigned short* qp = qkv + ((size_t)(b * SS + qbase + cl)) * 704 + h * 28;
#pragma unroll
    for (int e = 0; e < 8; ++e) {
      const int d = g * 8 + e;
      ((unsigned short*)&aq)[e] = (d < 28) ? qp[d] : (unsigned short)0;
    }
  }

  f32x4 o0 = {0.f, 0.f, 0.f, 0.f}, o1 = {0.f, 0.f, 0.f, 0.f};
  float m[4] = {-INFINITY, -INFINITY, -INFINITY, -INFINITY};
  float lsum[4] = {0.f, 0.f, 0.f, 0.f};

  const int ntiles = qt * 2 + 2;
  const int ntw = ((qbase + 15) >> 5) + 1;   // tiles this wave needs

  for (int tile = 0; tile < ntiles; ++tile) {
    const int t0 = tile * 32;
    __syncthreads();
    {
      const int r = tid >> 3, c4 = (tid & 7) << 2;
      const unsigned short* kp = qkv + ((size_t)(b * SS + t0 + r)) * 704 + 224 + h * 28 + c4;
      ushort4 ku = make_ushort4(0, 0, 0, 0), vu = make_ushort4(0, 0, 0, 0);
      if (c4 < 28) { ku = *(const ushort4*)kp; vu = *(const ushort4*)(kp + 224); }
      *(ushort4*)&Ks[r * 40 + c4] = ku;
      Vt[(c4 + 0) * 40 + r] = vu.x;
      Vt[(c4 + 1) * 40 + r] = vu.y;
      Vt[(c4 + 2) * 40 + r] = vu.z;
      Vt[(c4 + 3) * 40 + r] = vu.w;
    }
    __syncthreads();
    if (tile >= ntw) continue;

    const short8 bk0 = *(const short8*)&Ks[cl * 40 + g * 8];
    const short8 bk1 = *(const short8*)&Ks[(cl + 16) * 40 + g * 8];
    f32x4 zz = {0.f, 0.f, 0.f, 0.f};
    f32x4 s0 = __builtin_amdgcn_mfma_f32_16x16x32_bf16(aq, bk0, zz, 0, 0, 0);
    f32x4 s1 = __builtin_amdgcn_mfma_f32_16x16x32_bf16(aq, bk1, zz, 0, 0, 0);

    const bool diag = (t0 + 31 > qbase);
#pragma unroll
    for (int jj = 0; jj < 4; ++jj) {
      float v0 = s0[jj] * scale, v1 = s1[jj] * scale;
      if (diag) {
        const int qr = qbase + g * 4 + jj;
        if (t0 + cl > qr)      v0 = -INFINITY;
        if (t0 + 16 + cl > qr) v1 = -INFINITY;
      }
      float rm = fmaxf(v0, v1);
      rm = fmaxf(rm, __shfl_xor(rm, 1));
      rm = fmaxf(rm, __shfl_xor(rm, 2));
      rm = fmaxf(rm, __shfl_xor(rm, 4));
      rm = fmaxf(rm, __shfl_xor(rm, 8));
      const float mnew = fmaxf(m[jj], rm);
      const float r2 = __expf(m[jj] - mnew);   // first tile: exp(-inf)=0
      m[jj] = mnew;
      const float e0 = __expf(v0 - mnew), e1 = __expf(v1 - mnew);
      lsum[jj] = lsum[jj] * r2 + e0 + e1;
      o0[jj] *= r2; o1[jj] *= r2;
      Ps[w][(g * 4 + jj) * 40 + cl]      = f2b(e0);
      Ps[w][(g * 4 + jj) * 40 + cl + 16] = f2b(e1);
    }
    // PV: A = P (q x kv32), B = V^T-stored tile (kv x d)
    const short8 pa  = *(const short8*)&Ps[w][cl * 40 + g * 8];
    const short8 bv0 = *(const short8*)&Vt[cl * 40 + g * 8];
    const short8 bv1 = *(const short8*)&Vt[(cl + 16) * 40 + g * 8];
    o0 = __builtin_amdgcn_mfma_f32_16x16x32_bf16(pa, bv0, o0, 0, 0, 0);
    o1 = __builtin_amdgcn_mfma_f32_16x16x32_bf16(pa, bv1, o1, 0, 0, 0);
  }

#pragma unroll
  for (int jj = 0; jj < 4; ++jj) {
    float ls = lsum[jj];
    ls += __shfl_xor(ls, 1);
    ls += __shfl_xor(ls, 2);
    ls += __shfl_xor(ls, 4);
    ls += __shfl_xor(ls, 8);
    const float inv = 1.0f / ls;
    const int row = qbase + g * 4 + jj;
    unsigned short* op = o + ((size_t)(b * SS + row)) * 256 + h * 28;
    op[cl] = f2b(o0[jj] * inv);
    if (cl < 12) op[16 + cl] = f2b(o1[jj] * inv);
  }
}

// ---------------------------------------------------------------------------
// LayerNorm over (S,D) per batch, bf16 tensors (stride 256, 224 real cols).
// Stats come pre-reduced (2 floats per batch) from GEMM-epilogue atomics.
// ---------------------------------------------------------------------------
__global__ __launch_bounds__(256) void ln_apply(
    const unsigned short* __restrict__ x, const float* __restrict__ w,
    const float* __restrict__ bb, const float* __restrict__ st,
    unsigned short* __restrict__ y)
{
  const int b = blockIdx.x / 112;
  const float s1 = st[b * 2], s2 = st[b * 2 + 1];
  const float mu = s1 / (float)SD;
  const float rstd = rsqrtf(s2 / (float)SD - mu * mu + 1e-5f);
  const int chunk = blockIdx.x * 256 + threadIdx.x;
  const int r = chunk / 28, cc = chunk % 28;
  const int s = r & 1023;
  uint4 u = *(const uint4*)(x + (size_t)r * 256 + cc * 8);
  const float* wp = w + (size_t)s * 224 + cc * 8;
  const float* bp = bb + (size_t)s * 224 + cc * 8;
  float4 w0 = *(const float4*)wp, w1 = *(const float4*)(wp + 4);
  float4 b0 = *(const float4*)bp, b1 = *(const float4*)(bp + 4);
  float wv[8] = {w0.x, w0.y, w0.z, w0.w, w1.x, w1.y, w1.z, w1.w};
  float bv[8] = {b0.x, b0.y, b0.z, b0.w, b1.x, b1.y, b1.z, b1.w};
  const unsigned* up = (const unsigned*)&u;
  uint4 ov;
  unsigned* op = (unsigned*)&ov;
#pragma unroll
  for (int q = 0; q < 4; ++q) {
    float f0 = bits2f(up[q] << 16), f1 = bits2f(up[q] & 0xFFFF0000u);
    float y0 = (f0 - mu) * rstd * wv[q * 2] + bv[q * 2];
    float y1 = (f1 - mu) * rstd * wv[q * 2 + 1] + bv[q * 2 + 1];
    op[q] = (unsigned)f2b(y0) | ((unsigned)f2b(y1) << 16);
  }
  *(uint4*)(y + (size_t)r * 256 + cc * 8) = ov;
}

__global__ __launch_bounds__(256) void ln_part2(
    const unsigned short* __restrict__ x, const float* __restrict__ w,
    const float* __restrict__ bb, const float* __restrict__ stA,
    float* __restrict__ part2)
{
  const int b = blockIdx.y, g = blockIdx.x;
  const float s1 = stA[b * 2], s2 = stA[b * 2 + 1];
  const float mu = s1 / (float)SD;
  const float rstd = rsqrtf(s2 / (float)SD - mu * mu + 1e-5f);
  const unsigned short* base = x + ((size_t)b * 1024 + g * 16) * 256;
  float sum = 0.f, sq = 0.f;
  for (int c = threadIdx.x; c < 448; c += 256) {
    const int r = c / 28, cc = c % 28;
    const int s = g * 16 + r;
    uint4 u = *(const uint4*)(base + (size_t)r * 256 + cc * 8);
    const float* wp = w + (size_t)s * 224 + cc * 8;
    const float* bp = bb + (size_t)s * 224 + cc * 8;
    float4 w0 = *(const float4*)wp, w1 = *(const float4*)(wp + 4);
    float4 b0 = *(const float4*)bp, b1 = *(const float4*)(bp + 4);
    float wv[8] = {w0.x, w0.y, w0.z, w0.w, w1.x, w1.y, w1.z, w1.w};
    float bv[8] = {b0.x, b0.y, b0.z, b0.w, b1.x, b1.y, b1.z, b1.w};
    const unsigned* up = (const unsigned*)&u;
#pragma unroll
    for (int q = 0; q < 4; ++q) {
      float f0 = bits2f(up[q] << 16), f1 = bits2f(up[q] & 0xFFFF0000u);
      float y0 = (f0 - mu) * rstd * wv[q * 2] + bv[q * 2];
      float y1 = (f1 - mu) * rstd * wv[q * 2 + 1] + bv[q * 2 + 1];
      sum += y0 + y1; sq += y0 * y0 + y1 * y1;
    }
  }
  __shared__ float sA[4], sB[4];
#pragma unroll
  for (int o2 = 32; o2 > 0; o2 >>= 1) { sum += __shfl_down(sum, o2); sq += __shfl_down(sq, o2); }
  if ((threadIdx.x & 63) == 0) { sA[threadIdx.x >> 6] = sum; sB[threadIdx.x >> 6] = sq; }
  __syncthreads();
  if (threadIdx.x == 0) {
    part2[((size_t)b * 64 + g) * 2] = sA[0] + sA[1] + sA[2] + sA[3];
    part2[((size_t)b * 64 + g) * 2 + 1] = sB[0] + sB[1] + sB[2] + sB[3];
  }
}

__global__ __launch_bounds__(256) void ln_apply2(
    const unsigned short* __restrict__ x, const float* __restrict__ w,
    const float* __restrict__ bb, const float* __restrict__ stA,
    const float* __restrict__ part2, unsigned short* __restrict__ y)
{
  __shared__ float sh[2];
  const int tid = threadIdx.x;
  const int b = blockIdx.x / 112;
  const float s1 = stA[b * 2], s2 = stA[b * 2 + 1];
  const float mu1 = s1 / (float)SD;
  const float rs1 = rsqrtf(s2 / (float)SD - mu1 * mu1 + 1e-5f);
  if (tid < 64) {
    float p1 = part2[((size_t)b * 64 + tid) * 2];
    float p2 = part2[((size_t)b * 64 + tid) * 2 + 1];
#pragma unroll
    for (int o2 = 32; o2 > 0; o2 >>= 1) { p1 += __shfl_down(p1, o2); p2 += __shfl_down(p2, o2); }
    if (tid == 0) {
      float m2 = p1 / (float)SD;
      sh[0] = m2; sh[1] = rsqrtf(p2 / (float)SD - m2 * m2 + 1e-5f);
    }
  }
  __syncthreads();
  const float mu2 = sh[0], rs2 = sh[1];
  const int chunk = blockIdx.x * 256 + tid;
  const int r = chunk / 28, cc = chunk % 28;
  const int s = r & 1023;
  uint4 u = *(const uint4*)(x + (size_t)r * 256 + cc * 8);
  const float* wp = w + (size_t)s * 224 + cc * 8;
  const float* bp = bb + (size_t)s * 224 + cc * 8;
  float4 w0 = *(const float4*)wp, w1 = *(const float4*)(wp + 4);
  float4 b0 = *(const float4*)bp, b1 = *(const float4*)(bp + 4);
  float wv[8] = {w0.x, w0.y, w0.z, w0.w, w1.x, w1.y, w1.z, w1.w};
  float bv[8] = {b0.x, b0.y, b0.z, b0.w, b1.x, b1.y, b1.z, b1.w};
  const unsigned* up = (const unsigned*)&u;
  uint4 ov;
  unsigned* op = (unsigned*)&ov;
#pragma unroll
  for (int q = 0; q < 4; ++q) {
    float f0 = bits2f(up[q] << 16), f1 = bits2f(up[q] & 0xFFFF0000u);
    float y0 = (f0 - mu1) * rs1 * wv[q * 2] + bv[q * 2];
    float y1 = (f1 - mu1) * rs1 * wv[q * 2 + 1] + bv[q * 2 + 1];
    float z0 = (y0 - mu2) * rs2 * wv[q * 2] + bv[q * 2];
    float z1 = (y1 - mu2) * rs2 * wv[q * 2 + 1] + bv[q * 2 + 1];
    op[q] = (unsigned)f2b(z0) | ((unsigned)f2b(z1) << 16);
  }
  *(uint4*)(y + (size_t)r * 256 + cc * 8) = ov;
}

// ---------------------------------------------------------------------------
// Row softmax over V=8000, in place on d_out (fp32).
// ---------------------------------------------------------------------------
__global__ __launch_bounds__(256) void softmax_rows(float* __restrict__ logits)
{
  const int row = blockIdx.x;
  float* p = logits + (size_t)row * VV;
  __shared__ float buf[VV];
  __shared__ float red[4];
  const int tid = threadIdx.x;

  float mx = -INFINITY;
  for (int i = tid; i < VV; i += 256) { float v = p[i]; buf[i] = v; mx = fmaxf(mx, v); }
#pragma unroll
  for (int o2 = 32; o2 > 0; o2 >>= 1) mx = fmaxf(mx, __shfl_down(mx, o2));
  if ((tid & 63) == 0) red[tid >> 6] = mx;
  __syncthreads();
  mx = fmaxf(fmaxf(red[0], red[1]), fmaxf(red[2], red[3]));
  __syncthreads();

  float s = 0.f;
  for (int i = tid; i < VV; i += 256) { float e = __expf(buf[i] - mx); buf[i] = e; s += e; }
#pragma unroll
  for (int o2 = 32; o2 > 0; o2 >>= 1) s += __shfl_down(s, o2);
  if ((tid & 63) == 0) red[tid >> 6] = s;
  __syncthreads();
  s = red[0] + red[1] + red[2] + red[3];
  const float inv = 1.0f / s;
  for (int i = tid; i < VV; i += 256) p[i] = buf[i] * inv;
}

// ---------------------------------------------------------------------------
extern "C" void kernel_launch(void* const* d_in, const int* in_sizes, int n_in,
                              void* d_out, int out_size, void* d_ws, size_t ws_size,
                              hipStream_t stream) {
  const float* x   = (const float*)d_in[0];
  const float* Wp  = (const float*)d_in[1];
  const float* bp  = (const float*)d_in[2];
  const float* Wq  = (const float*)d_in[3];
  const float* bq  = (const float*)d_in[4];
  const float* Wk  = (const float*)d_in[5];
  const float* bk  = (const float*)d_in[6];
  const float* Wv  = (const float*)d_in[7];
  const float* bv  = (const float*)d_in[8];
  const float* Wo  = (const float*)d_in[9];
  const float* bo  = (const float*)d_in[10];
  const float* W1  = (const float*)d_in[11];
  const float* b1  = (const float*)d_in[12];
  const float* W2  = (const float*)d_in[13];
  const float* b2  = (const float*)d_in[14];
  const float* W3  = (const float*)d_in[15];
  const float* b3  = (const float*)d_in[16];
  const float* lnw = (const float*)d_in[17];
  const float* lnb = (const float*)d_in[18];
  const float* Wf  = (const float*)d_in[19];
  const float* bf  = (const float*)d_in[20];

  unsigned short* wsb = (unsigned short*)d_ws;
  unsigned short* wpT   = wsb + WP;
  unsigned short* wqkvT = wsb + WQKV;
  unsigned short* woT   = wsb + WO;
  unsigned short* w1T   = wsb + W1T;
  unsigned short* w2T   = wsb + W2T;
  unsigned short* w3T   = wsb + W3T;
  unsigned short* wfT   = wsb + WFT;
  unsigned short* h     = wsb + HB;
  unsigned short* h2    = wsb + H2B;
  unsigned short* obuf  = wsb + OBUF;
  unsigned short* xb    = wsb + BIG;
  unsigned short* qkvb  = wsb + BIG;
  unsigned short* f1    = wsb + BIG;
  unsigned short* f2    = wsb + BIG + (size_t)4096 * 640;
  float* bcat  = (float*)((char*)d_ws + FBYTE);
  float* part2 = bcat + LLl * 672;
  float* stats = part2 + 512;     // 128 floats: 8 layers x 2 slots x (4 batches x 2)

  // ---- prep ----
  zero_stats<<<1, 128, 0, stream>>>(stats);
  prep_x<<<3072, 256, 0, stream>>>(x, xb);
  prep_wt2<<<dim3(192, 1), 256, 0, stream>>>(Wp, wpT, 768, 224, 768, 256, 0, 0);
  prep_wqkv<<<dim3(704, 8), 256, 0, stream>>>(Wq, Wk, Wv, bq, bk, bv, wqkvT, bcat);
  prep_wt2<<<dim3(64, 8), 256, 0, stream>>>(Wo, woT, 224, 224, 256, 256,
                                            (size_t)224 * 224, (size_t)256 * 256);
  prep_wt2<<<dim3(160, 8), 256, 0, stream>>>(W1, w1T, 224, 600, 256, 640,
                                             (size_t)224 * 600, (size_t)640 * 256);
  prep_wt2<<<dim3(400, 8), 256, 0, stream>>>(W2, w2T, 600, 600, 640, 640,
                                             (size_t)600 * 600, (size_t)640 * 640);
  prep_wt2<<<dim3(160, 8), 256, 0, stream>>>(W3, w3T, 600, 224, 640, 256,
                                             (size_t)600 * 224, (size_t)256 * 640);
  prep_wt2<<<dim3(2016, 1), 256, 0, stream>>>(Wf, wfT, 224, 8000, 256, 8064, 0, 0);

  // ---- proj + posenc: h = x @ Wp + bp + pe ----
  gemm_mfma<64, 64, GF_BIAS | GF_POSENC><<<dim3(4, 64), 256, 0, stream>>>(
      xb, wpT, bp, nullptr, h, 768, 224, 256, nullptr);

  for (int l = 0; l < LLl; ++l) {
    float* stA = stats + (size_t)(l * 2) * 8;
    float* stB = stats + (size_t)(l * 2 + 1) * 8;
    gemm_mfma<128, 64, GF_BIAS><<<dim3(11, 32), 256, 0, stream>>>(
        h, wqkvT + (size_t)l * 704 * 256, bcat + l * 672, nullptr, qkvb, 256, 672, 704, nullptr);
    attn_mfma<<<dim3(BB * 8, SS / 64), 256, 0, stream>>>(qkvb, obuf);
    gemm_mfma<64, 64, GF_BIAS | GF_RESID | GF_STAT><<<dim3(4, 64), 256, 0, stream>>>(
        obuf, woT + (size_t)l * 256 * 256, bo + (size_t)l * 224, h, h2, 256, 224, 256, stA);
    ln_apply<<<448, 256, 0, stream>>>(h2, lnw + (size_t)l * SD, lnb + (size_t)l * SD, stA, h);
    gemm_mfma<128, 64, GF_BIAS | GF_RELU><<<dim3(10, 32), 256, 0, stream>>>(
        h, w1T + (size_t)l * 640 * 256, b1 + (size_t)l * 600, nullptr, f1, 256, 600, 640, nullptr);
    gemm_mfma<128, 64, GF_BIAS | GF_RELU><<<dim3(10, 32), 256, 0, stream>>>(
        f1, w2T + (size_t)l * 640 * 640, b2 + (size_t)l * 600, nullptr, f2, 640, 600, 640, nullptr);
    gemm_mfma<64, 64, GF_BIAS | GF_RESID | GF_STAT><<<dim3(4, 64), 256, 0, stream>>>(
        f2, w3T + (size_t)l * 256 * 640, b3 + (size_t)l * 224, h, h2, 640, 224, 256, stB);
    ln_part2<<<dim3(64, BB), 256, 0, stream>>>(h2, lnw + (size_t)l * SD, lnb + (size_t)l * SD,
                                               stB, part2);
    ln_apply2<<<448, 256, 0, stream>>>(h2, lnw + (size_t)l * SD, lnb + (size_t)l * SD,
                                       stB, part2, h);
  }

  // ---- logits (fp32 out, m-fastest block order) + softmax ----
  gemm_mfma<128, 128, GF_BIAS | GF_F32OUT | GF_SWAP><<<dim3(32, 63), 256, 0, stream>>>(
      h, wfT, bf, nullptr, (float*)d_out, 256, 8000, 8000, nullptr);
  softmax_rows<<<4096, 256, 0, stream>>>((float*)d_out);
}